// Round 13
// baseline (256.305 us; speedup 1.0000x reference)
//
#include <hip/hip_runtime.h>
#include <math.h>

#define BB   128
#define TT   64
#define IND  128
#define HID  256
#define CD   384   // comb dim = IND + HID

typedef float v2f __attribute__((ext_vector_type(2)));

struct C2 { float x, y; };
__device__ __forceinline__ C2 cmul(C2 a, C2 b) { return {a.x*b.x - a.y*b.y, a.x*b.y + a.y*b.x}; }
__device__ __forceinline__ C2 cadd(C2 a, C2 b) { return {a.x + b.x, a.y + b.y}; }
__device__ __forceinline__ C2 csub(C2 a, C2 b) { return {a.x - b.x, a.y - b.y}; }
__device__ __forceinline__ C2 conjc(C2 a) { return {a.x, -a.y}; }

__device__ __forceinline__ v2f pk(float a, float b) { v2f r; r.x = a; r.y = b; return r; }
__device__ __forceinline__ v2f swp(v2f v) { return __builtin_shufflevector(v, v, 1, 0); }

struct Args {
    const float* x;
    const float* W[4];
    const float* bb[4];
    const float* qp[4];
    const float* Uo[4];
    const float* cb[4];
    float* out;
};

template<int CTRL>
__device__ __forceinline__ int dppmv(int v) {
    return __builtin_amdgcn_update_dpp(v, v, CTRL, 0xF, 0xF, false);
}

// Lane-xor exchange (R9-R12 proven, all-VALU).
template<int M>
__device__ __forceinline__ float lx(float v) {
    int i = __float_as_int(v);
    if constexpr (M == 1)
        return __int_as_float(dppmv<0xB1>(i));            // quad_perm [1,0,3,2]
    else if constexpr (M == 2)
        return __int_as_float(dppmv<0x4E>(i));            // quad_perm [2,3,0,1]
    else if constexpr (M == 4) {
        int a = dppmv<0x104>(i);                          // row_shl:4
        int b = dppmv<0x114>(i);                          // row_shr:4
        return __int_as_float((threadIdx.x & 4) ? b : a);
    } else if constexpr (M == 8)
        return __int_as_float(dppmv<0x128>(i));           // row_ror:8 == xor8
    else if constexpr (M == 16) {
#if __has_builtin(__builtin_amdgcn_permlane16_swap)
        auto r = __builtin_amdgcn_permlane16_swap(i, i, false, false);
        return __int_as_float((threadIdx.x & 16) ? r[0] : r[1]);
#else
        return __int_as_float(__builtin_amdgcn_ds_swizzle(i, 0x401F));
#endif
    } else {
#if __has_builtin(__builtin_amdgcn_permlane32_swap)
        auto r = __builtin_amdgcn_permlane32_swap(i, i, false, false);
        return __int_as_float((threadIdx.x & 32) ? r[0] : r[1]);
#else
        return __shfl_xor(v, 32);
#endif
    }
}
template<int M>
__device__ __forceinline__ v2f lx2(v2f v) {
    return pk(lx<M>(v.x), lx<M>(v.y));
}

__device__ __forceinline__ float rfl(float v) {
    return __int_as_float(__builtin_amdgcn_readfirstlane(__float_as_int(v)));
}
__device__ __forceinline__ float bcast_lane(float v, int srclane) {
    return __int_as_float(__builtin_amdgcn_readlane(__float_as_int(v), srclane));
}
__device__ __forceinline__ float sigm(float x) {
    return __builtin_amdgcn_rcpf(1.f + __expf(-x));
}
__device__ __forceinline__ float tanh_fast(float x) {
    float e = __expf(2.f * x);
    return 1.f - 2.f * __builtin_amdgcn_rcpf(e + 1.f);
}
__device__ __forceinline__ float sgnx(float v, unsigned m) {
    return __int_as_float(__float_as_int(v) ^ (int)m);
}

// Packed SU(2) lane-gate on both reg-pairs; u0..u3 per-lane scalars.
template<int M>
__device__ __forceinline__ void gate_lane_pk(v2f& xe01, v2f& xi01, v2f& xe23, v2f& xi23,
                                             float u0, float u1, float u2, float u3) {
    v2f px0 = lx2<M>(xe01), py0 = lx2<M>(xi01);
    v2f px2 = lx2<M>(xe23), py2 = lx2<M>(xi23);
    v2f ne0 = u0*xe01 - u1*xi01 + u2*px0 - u3*py0;
    v2f ni0 = u0*xi01 + u1*xe01 + u2*py0 + u3*px0;
    v2f ne2 = u0*xe23 - u1*xi23 + u2*px2 - u3*py2;
    v2f ni2 = u0*xi23 + u1*xe23 + u2*py2 + u3*px2;
    xe01 = ne0; xi01 = ni0; xe23 = ne2; xi23 = ni2;
}

__global__ __launch_bounds__(256, 1) void qlstm_kernel(Args a) {
    const int b0   = blockIdx.x * 2, b1 = b0 + 1;   // two samples per block
    const int tid  = threadIdx.x;
    const int lane = tid & 63;
    const int wv   = tid >> 6;          // wave id == gate id (f,i,g,o)

    __shared__ float Ax[2][TT][32];                    // x-part of angles per sample
    __shared__ __align__(16) float hH[2][16][HID];     // h history rings
    __shared__ __align__(16) float4 uab[4][2][8];      // SU(2) (ax,ay,bx,by) per gate
    __shared__ __align__(16) float expL[2][32];        // <Z_q>, [sample][q*4+gate]

    const int a_ang = tid >> 3, p = tid & 7;
    const int g_ang = a_ang >> 3, q_ang = a_ang & 7;
    v2f whr2[8][2];
    {
        const float* Wg = a.W[g_ang] + q_ang * CD + IND;
#pragma unroll
        for (int k = 0; k < 8; ++k) {
            int base = p * 32 + ((4 * (k + p)) & 31);
            whr2[k][0] = pk(Wg[base + 0], Wg[base + 1]);
            whr2[k][1] = pk(Wg[base + 2], Wg[base + 3]);
        }
    }
    v2f ur2a[8], ur2b[8], cb2a, cb2b;
#pragma unroll
    for (int k = 0; k < 8; ++k) {
        ur2a[k] = pk(a.Uo[0][tid * 8 + k], a.Uo[1][tid * 8 + k]);
        ur2b[k] = pk(a.Uo[2][tid * 8 + k], a.Uo[3][tid * 8 + k]);
    }
    cb2a = pk(a.cb[0][tid], a.cb[1][tid]);
    cb2b = pk(a.cb[2][tid], a.cb[3][tid]);

    // ---- SU(2) parameter unitaries alpha,beta = Rz*Ry*Rx (once) ----
    if (tid < 64) {
        int g = tid >> 4, d = (tid >> 3) & 1, q = tid & 7;
        const float* qp = a.qp[g] + q * 6 + d * 3;
        float s0, c0, s1, c1, s2, c2;
        sincosf(0.5f * qp[0], &s0, &c0);
        sincosf(0.5f * qp[1], &s1, &c1);
        sincosf(0.5f * qp[2], &s2, &c2);
        C2 aX{c0, 0.f}, bX{0.f, -s0};
        C2 aY{c1, 0.f}, bY{-s1, 0.f};
        C2 aB = csub(cmul(aY, aX), cmul(bY, conjc(bX)));
        C2 bB = cadd(cmul(aY, bX), cmul(bY, conjc(aX)));
        C2 aZ{c2, -s2};
        C2 al = cmul(aZ, aB), be = cmul(aZ, bB);
        uab[g][d][q] = make_float4(al.x, al.y, be.x, be.y);
    }

    // ---- x-part of angles, both samples, all timesteps ----
    for (int rep = 0; rep < 16; ++rep) {
        int idx = rep * 256 + tid;
        int s = idx >> 11, t = (idx >> 5) & 63, aa = idx & 31;
        int gg = aa >> 3, qq = aa & 7;
        const float4* w4 = (const float4*)(a.W[gg] + qq * CD);
        const float4* x4 = (const float4*)(a.x + (size_t)(t * BB + b0 + s) * IND);
        float acc = a.bb[gg][qq];
        for (int e = 0; e < IND / 4; ++e) {
            float4 xv = x4[e], wvv = w4[e];
            acc += xv.x * wvv.x + xv.y * wvv.y + xv.z * wvv.z + xv.w * wvv.w;
        }
        Ax[s][t][aa] = acc;
    }

    hH[0][15][tid] = 0.f;
    hH[1][15][tid] = 0.f;
    float creg0 = 0.f, h0 = 0.f, creg1 = 0.f, h1 = 0.f;
    __syncthreads();

    // ---- d=0 unitaries prepacked (shared by both samples) ----
    v2f pA[8], pB[8], pC[8], pD[8];
#pragma unroll
    for (int q = 0; q < 8; ++q) {
        float4 u = uab[wv][0][q];
        float ax = rfl(u.x), ay = rfl(u.y), bx = rfl(u.z), by = rfl(u.w);
        pA[q] = pk(ax, -bx);
        pB[q] = pk(by, -ay);
        pC[q] = pk(ay, by);
        pD[q] = pk(-bx, -ax);
    }
    float gA[6][4];
#pragma unroll
    for (int qi = 0; qi < 6; ++qi) {
        float4 u = uab[wv][1][qi + 2];
        bool bit = (lane >> (5 - qi)) & 1;
        gA[qi][0] = u.x;
        gA[qi][1] = bit ? -u.y : u.y;
        gA[qi][2] = bit ? -u.z : u.z;
        gA[qi][3] = u.w;
    }
    float q0ax, q0ay, q0bx, q0by, q1ax, q1by;
    v2f q1aym, q1ayp, q1bxm;
    {
        float4 u0 = uab[wv][1][0], u1 = uab[wv][1][1];
        q0ax = rfl(u0.x); q0ay = rfl(u0.y); q0bx = rfl(u0.z); q0by = rfl(u0.w);
        q1ax = rfl(u1.x); q1by = rfl(u1.w);
        float ay = rfl(u1.y), bx = rfl(u1.z);
        q1aym = pk(-ay, ay);
        q1ayp = pk(ay, -ay);
        q1bxm = pk(bx, -bx);
    }

    // ---- d=0 CNOT fold selectors (proven R11/R12) ----
    const bool st3 = ((lane >> 4) ^ (lane >> 5)) & 1;
    const bool st4 = ((lane >> 3) ^ (lane >> 4)) & 1;
    const bool st5 = ((lane >> 2) ^ (lane >> 3)) & 1;
    const bool st6 = ((lane >> 1) ^ (lane >> 2)) & 1;
    const bool st7 = (lane ^ (lane >> 1)) & 1;
    const bool sp2 = (lane >> 5) & 1;
    const bool sp7 = lane & 1;

    // ---- measurement sign masks (proven R10) ----
    unsigned sg0, sg2, sg3, sg4, sg5, sg6, sg7;
    {
        auto par31 = [](int v) -> unsigned { return (unsigned)(__popc(v) & 1) << 31; };
        sg0 = par31(lane & 63);
        sg2 = par31(lane & 32);
        sg3 = par31(lane & 48);
        sg4 = par31(lane & 56);
        sg5 = par31(lane & 60);
        sg6 = par31(lane & 62);
        sg7 = sg0;
    }

    // ---- circuit body (R12-verbatim math), reused for both samples ----
    auto run_circuit = [&](const float (&cs_c)[8], const float (&cs_s)[8],
                           v2f& xe01, v2f& xi01, v2f& xe23, v2f& xi23) {
        v2f Vx[8], Vy[8];
#pragma unroll
        for (int q = 0; q < 8; ++q) {
            Vx[q] = pA[q] * cs_c[q] + pB[q] * cs_s[q];
            Vy[q] = pC[q] * cs_c[q] + pD[q] * cs_s[q];
        }
        {
            C2 f3{ st3 ? Vx[3].y : Vx[3].x, st3 ? Vy[3].y : Vy[3].x };
            C2 f4{ st4 ? Vx[4].y : Vx[4].x, st4 ? Vy[4].y : Vy[4].x };
            C2 f5{ st5 ? Vx[5].y : Vx[5].x, st5 ? Vy[5].y : Vy[5].x };
            C2 f6{ st6 ? Vx[6].y : Vx[6].x, st6 ? Vy[6].y : Vy[6].x };
            C2 f7{ st7 ? Vx[7].y : Vx[7].x, st7 ? Vy[7].y : Vy[7].x };
            C2 c5 = cmul(cmul(cmul(f3, f4), cmul(f5, f6)), f7);
            v2f f2re = sp2 ? swp(Vx[2]) : Vx[2];
            v2f f2im = sp2 ? swp(Vy[2]) : Vy[2];
            v2f c2re = c5.x * f2re - c5.y * f2im;
            v2f c2im = c5.x * f2im + c5.y * f2re;
            v2f f1re = sp7 ? swp(Vx[1]) : Vx[1];
            v2f f1im = sp7 ? swp(Vy[1]) : Vy[1];
            float f0ax = sp7 ? Vx[0].y : Vx[0].x, f0ay = sp7 ? Vy[0].y : Vy[0].x;
            float f0bx = sp7 ? Vx[0].x : Vx[0].y, f0by = sp7 ? Vy[0].x : Vy[0].y;
            v2f uure = f1re * f0ax - f1im * f0ay;
            v2f uuim = f1re * f0ay + f1im * f0ax;
            v2f s1re = swp(f1re), s1im = swp(f1im);
            v2f wwre = s1re * f0bx - s1im * f0by;
            v2f wwim = s1re * f0by + s1im * f0bx;
            xe01 = c2re * uure - c2im * uuim;
            xi01 = c2re * uuim + c2im * uure;
            xe23 = c2re * wwre - c2im * wwim;
            xi23 = c2re * wwim + c2im * wwre;
        }
        { // qubit 0
            v2f ne01 = q0ax*xe01 - q0ay*xi01 + q0bx*xe23 - q0by*xi23;
            v2f ni01 = q0ax*xi01 + q0ay*xe01 + q0bx*xi23 + q0by*xe23;
            v2f ne23 = -q0bx*xe01 - q0by*xi01 + q0ax*xe23 + q0ay*xi23;
            v2f ni23 = -q0bx*xi01 + q0by*xe01 + q0ax*xi23 - q0ay*xe23;
            xe01 = ne01; xi01 = ni01; xe23 = ne23; xi23 = ni23;
        }
        { // qubit 1
            v2f se01 = swp(xe01), si01 = swp(xi01);
            v2f se23 = swp(xe23), si23 = swp(xi23);
            v2f ne01 = q1ax*xe01 + q1aym*xi01 + q1bxm*se01 - q1by*si01;
            v2f ni01 = q1ax*xi01 + q1ayp*xe01 + q1bxm*si01 + q1by*se01;
            v2f ne23 = q1ax*xe23 + q1aym*xi23 + q1bxm*se23 - q1by*si23;
            v2f ni23 = q1ax*xi23 + q1ayp*xe23 + q1bxm*si23 + q1by*se23;
            xe01 = ne01; xi01 = ni01; xe23 = ne23; xi23 = ni23;
        }
        gate_lane_pk<32>(xe01, xi01, xe23, xi23, gA[0][0], gA[0][1], gA[0][2], gA[0][3]);
        gate_lane_pk<16>(xe01, xi01, xe23, xi23, gA[1][0], gA[1][1], gA[1][2], gA[1][3]);
        gate_lane_pk< 8>(xe01, xi01, xe23, xi23, gA[2][0], gA[2][1], gA[2][2], gA[2][3]);
        gate_lane_pk< 4>(xe01, xi01, xe23, xi23, gA[3][0], gA[3][1], gA[3][2], gA[3][3]);
        gate_lane_pk< 2>(xe01, xi01, xe23, xi23, gA[4][0], gA[4][1], gA[4][2], gA[4][3]);
        gate_lane_pk< 1>(xe01, xi01, xe23, xi23, gA[5][0], gA[5][1], gA[5][2], gA[5][3]);
    };

    auto butterfly = [&](v2f xe01, v2f xi01, v2f xe23, v2f xi23,
                         v2f& zA, v2f& zB, v2f& zC, v2f& zD) {
        v2f pr01 = xe01 * xe01 + xi01 * xi01;
        v2f pr23 = xe23 * xe23 + xi23 * xi23;
        float pr0 = pr01.x, pr1 = pr01.y, pr2 = pr23.x, pr3 = pr23.y;
        float Bc = pr0 - pr1 + pr2 - pr3;
        float Dc = pr0 - pr1 - pr2 + pr3;
        zA = pk(sgnx(Bc, sg0), Dc);
        zB = pk(sgnx(Dc, sg2), sgnx(Dc, sg3));
        zC = pk(sgnx(Dc, sg4), sgnx(Dc, sg5));
        zD = pk(sgnx(Dc, sg6), sgnx(Dc, sg7));
        zA = zA + lx2<1>(zA);  zB = zB + lx2<1>(zB);  zC = zC + lx2<1>(zC);  zD = zD + lx2<1>(zD);
        zA = zA + lx2<2>(zA);  zB = zB + lx2<2>(zB);  zC = zC + lx2<2>(zC);  zD = zD + lx2<2>(zD);
        zA = zA + lx2<4>(zA);  zB = zB + lx2<4>(zB);  zC = zC + lx2<4>(zC);  zD = zD + lx2<4>(zD);
        zA = zA + lx2<8>(zA);  zB = zB + lx2<8>(zB);  zC = zC + lx2<8>(zC);  zD = zD + lx2<8>(zD);
        zA = zA + lx2<16>(zA); zB = zB + lx2<16>(zB); zC = zC + lx2<16>(zC); zD = zD + lx2<16>(zD);
        zA = zA + lx2<32>(zA); zB = zB + lx2<32>(zB); zC = zC + lx2<32>(zC); zD = zD + lx2<32>(zD);
    };

    for (int t = 0; t < TT; ++t) {
        // ---- angle stage, both samples ----
        const int rowPrev = (t + 15) & 15;
        const float* hrow0 = hH[0][rowPrev];
        const float* hrow1 = hH[1][rowPrev];
        v2f acc2_0 = pk(0.f, 0.f), acc2_1 = pk(0.f, 0.f);
#pragma unroll
        for (int k = 0; k < 8; ++k) {
            int base = p * 32 + ((4 * (k + p)) & 31);
            const float4 hv0 = *reinterpret_cast<const float4*>(&hrow0[base]);
            const float4 hv1 = *reinterpret_cast<const float4*>(&hrow1[base]);
            acc2_0 = acc2_0 + pk(hv0.x, hv0.y) * whr2[k][0] + pk(hv0.z, hv0.w) * whr2[k][1];
            acc2_1 = acc2_1 + pk(hv1.x, hv1.y) * whr2[k][0] + pk(hv1.z, hv1.w) * whr2[k][1];
        }
        float acc0 = acc2_0.x + acc2_0.y;
        float acc1 = acc2_1.x + acc2_1.y;
        acc0 += lx<1>(acc0);  acc1 += lx<1>(acc1);
        acc0 += lx<2>(acc0);  acc1 += lx<2>(acc1);
        acc0 += lx<4>(acc0);  acc1 += lx<4>(acc1);
        float ang0 = 0.5f * (acc0 + Ax[0][t][a_ang]);
        float ang1 = 0.5f * (acc1 + Ax[1][t][a_ang]);
        float cA0 = __cosf(ang0), sA0 = __sinf(ang0);
        float cA1 = __cosf(ang1), sA1 = __sinf(ang1);
        float cs_c0[8], cs_s0[8], cs_c1[8], cs_s1[8];
#pragma unroll
        for (int q = 0; q < 8; ++q) {
            cs_c0[q] = bcast_lane(cA0, q * 8);
            cs_s0[q] = bcast_lane(sA0, q * 8);
            cs_c1[q] = bcast_lane(cA1, q * 8);
            cs_s1[q] = bcast_lane(sA1, q * 8);
        }

        // ---- circuits (independent -> compiler interleaves; ILP fills stalls) ----
        v2f xe01_0, xi01_0, xe23_0, xi23_0;
        v2f xe01_1, xi01_1, xe23_1, xi23_1;
        run_circuit(cs_c0, cs_s0, xe01_0, xi01_0, xe23_0, xi23_0);
        run_circuit(cs_c1, cs_s1, xe01_1, xi01_1, xe23_1, xi23_1);

        v2f zA0, zB0, zC0, zD0, zA1, zB1, zC1, zD1;
        butterfly(xe01_0, xi01_0, xe23_0, xi23_0, zA0, zB0, zC0, zD0);
        butterfly(xe01_1, xi01_1, xe23_1, xi23_1, zA1, zB1, zC1, zD1);

        // all lanes hold totals -> lane0 writes s0, lane1 writes s1 (parallel)
        if (lane == 0) {
            expL[0][0*4 + wv] = zA0.x; expL[0][1*4 + wv] = zA0.y;
            expL[0][2*4 + wv] = zB0.x; expL[0][3*4 + wv] = zB0.y;
            expL[0][4*4 + wv] = zC0.x; expL[0][5*4 + wv] = zC0.y;
            expL[0][6*4 + wv] = zD0.x; expL[0][7*4 + wv] = zD0.y;
        }
        if (lane == 1) {
            expL[1][0*4 + wv] = zA1.x; expL[1][1*4 + wv] = zA1.y;
            expL[1][2*4 + wv] = zB1.x; expL[1][3*4 + wv] = zB1.y;
            expL[1][4*4 + wv] = zC1.x; expL[1][5*4 + wv] = zC1.y;
            expL[1][6*4 + wv] = zD1.x; expL[1][7*4 + wv] = zD1.y;
        }
        __syncthreads();

        // ---- output projection + LSTM pointwise, both samples ----
        {
            const float4* eL4 = (const float4*)expL[0];
            v2f og2a = cb2a, og2b = cb2b;
#pragma unroll
            for (int k = 0; k < 8; ++k) {
                float4 e4 = eL4[k];
                og2a = og2a + pk(e4.x, e4.y) * ur2a[k];
                og2b = og2b + pk(e4.z, e4.w) * ur2b[k];
            }
            float fg = sigm(og2a.x);
            float ig = sigm(og2a.y);
            float gg = tanh_fast(og2b.x);
            float oo = sigm(og2b.y);
            creg0 = fg * creg0 + ig * gg;
            h0 = oo * tanh_fast(creg0);
        }
        {
            const float4* eL4 = (const float4*)expL[1];
            v2f og2a = cb2a, og2b = cb2b;
#pragma unroll
            for (int k = 0; k < 8; ++k) {
                float4 e4 = eL4[k];
                og2a = og2a + pk(e4.x, e4.y) * ur2a[k];
                og2b = og2b + pk(e4.z, e4.w) * ur2b[k];
            }
            float fg = sigm(og2a.x);
            float ig = sigm(og2a.y);
            float gg = tanh_fast(og2b.x);
            float oo = sigm(og2b.y);
            creg1 = fg * creg1 + ig * gg;
            h1 = oo * tanh_fast(creg1);
        }

        hH[0][t & 15][tid] = h0;
        hH[1][t & 15][tid] = h1;
        if ((t & 15) == 15) {
            int t0 = t - 15;
#pragma unroll
            for (int r = 0; r < 16; ++r) {
                a.out[(size_t)((t0 + r) * BB + b0) * HID + tid] = hH[0][r][tid];
                a.out[(size_t)((t0 + r) * BB + b1) * HID + tid] = hH[1][r][tid];
            }
        }
        __syncthreads();
    }

    a.out[(size_t)TT * BB * HID + (size_t)b0 * HID + tid] = h0;
    a.out[(size_t)TT * BB * HID + (size_t)b1 * HID + tid] = h1;
    a.out[(size_t)TT * BB * HID + (size_t)BB * HID + (size_t)b0 * HID + tid] = creg0;
    a.out[(size_t)TT * BB * HID + (size_t)BB * HID + (size_t)b1 * HID + tid] = creg1;
}

extern "C" void kernel_launch(void* const* d_in, const int* in_sizes, int n_in,
                              void* d_out, int out_size, void* d_ws, size_t ws_size,
                              hipStream_t stream) {
    (void)in_sizes; (void)n_in; (void)out_size; (void)d_ws; (void)ws_size;
    Args ar;
    ar.x = (const float*)d_in[0];
    for (int g = 0; g < 4; ++g) {
        ar.W[g]  = (const float*)d_in[1 + 5 * g];
        ar.bb[g] = (const float*)d_in[2 + 5 * g];
        ar.qp[g] = (const float*)d_in[3 + 5 * g];
        ar.Uo[g] = (const float*)d_in[4 + 5 * g];
        ar.cb[g] = (const float*)d_in[5 + 5 * g];
    }
    ar.out = (float*)d_out;
    qlstm_kernel<<<dim3(BB / 2), dim3(256), 0, stream>>>(ar);
}

// Round 14
// 246.004 us; speedup vs baseline: 1.0419x; 1.0419x over previous
//
#include <hip/hip_runtime.h>
#include <math.h>

#define BB   128
#define TT   64
#define IND  128
#define HID  256
#define CD   384   // comb dim = IND + HID

typedef float v2f __attribute__((ext_vector_type(2)));

struct C2 { float x, y; };
__device__ __forceinline__ C2 cmul(C2 a, C2 b) { return {a.x*b.x - a.y*b.y, a.x*b.y + a.y*b.x}; }
__device__ __forceinline__ C2 cadd(C2 a, C2 b) { return {a.x + b.x, a.y + b.y}; }
__device__ __forceinline__ C2 csub(C2 a, C2 b) { return {a.x - b.x, a.y - b.y}; }
__device__ __forceinline__ C2 conjc(C2 a) { return {a.x, -a.y}; }

__device__ __forceinline__ v2f pk(float a, float b) { v2f r; r.x = a; r.y = b; return r; }
__device__ __forceinline__ v2f swp(v2f v) { return __builtin_shufflevector(v, v, 1, 0); }

struct Args {
    const float* x;
    const float* W[4];
    const float* bb[4];
    const float* qp[4];
    const float* Uo[4];
    const float* cb[4];
    float* out;
};

template<int CTRL>
__device__ __forceinline__ int dppmv(int v) {
    return __builtin_amdgcn_update_dpp(v, v, CTRL, 0xF, 0xF, false);
}

// Lane-xor exchange (R9-R12 proven, all-VALU).
template<int M>
__device__ __forceinline__ float lx(float v) {
    int i = __float_as_int(v);
    if constexpr (M == 1)
        return __int_as_float(dppmv<0xB1>(i));
    else if constexpr (M == 2)
        return __int_as_float(dppmv<0x4E>(i));
    else if constexpr (M == 4) {
        int a = dppmv<0x104>(i);
        int b = dppmv<0x114>(i);
        return __int_as_float((threadIdx.x & 4) ? b : a);
    } else if constexpr (M == 8)
        return __int_as_float(dppmv<0x128>(i));
    else if constexpr (M == 16) {
#if __has_builtin(__builtin_amdgcn_permlane16_swap)
        auto r = __builtin_amdgcn_permlane16_swap(i, i, false, false);
        return __int_as_float((threadIdx.x & 16) ? r[0] : r[1]);
#else
        return __int_as_float(__builtin_amdgcn_ds_swizzle(i, 0x401F));
#endif
    } else {
#if __has_builtin(__builtin_amdgcn_permlane32_swap)
        auto r = __builtin_amdgcn_permlane32_swap(i, i, false, false);
        return __int_as_float((threadIdx.x & 32) ? r[0] : r[1]);
#else
        return __shfl_xor(v, 32);
#endif
    }
}
template<int M>
__device__ __forceinline__ v2f lx2(v2f v) {
    return pk(lx<M>(v.x), lx<M>(v.y));
}

__device__ __forceinline__ float rfl(float v) {
    return __int_as_float(__builtin_amdgcn_readfirstlane(__float_as_int(v)));
}
__device__ __forceinline__ float bcast_lane(float v, int srclane) {
    return __int_as_float(__builtin_amdgcn_readlane(__float_as_int(v), srclane));
}
__device__ __forceinline__ float sigm(float x) {
    return __builtin_amdgcn_rcpf(1.f + __expf(-x));
}
__device__ __forceinline__ float tanh_fast(float x) {
    float e = __expf(2.f * x);
    return 1.f - 2.f * __builtin_amdgcn_rcpf(e + 1.f);
}
__device__ __forceinline__ float sgnx(float v, unsigned m) {
    return __int_as_float(__float_as_int(v) ^ (int)m);
}

// Fused dual-sample packed SU(2) lane-gate: statements interleaved A/B so the
// scheduler always has an independent instruction adjacent (R13 lesson: the
// lambda-called-twice version serialized; VGPR stayed 196).
template<int M>
__device__ __forceinline__ void gate_lane_pk2(
        v2f& ae01, v2f& ai01, v2f& ae23, v2f& ai23,
        v2f& be01, v2f& bi01, v2f& be23, v2f& bi23,
        float u0, float u1, float u2, float u3) {
    v2f pxa0 = lx2<M>(ae01);  v2f pxb0 = lx2<M>(be01);
    v2f pya0 = lx2<M>(ai01);  v2f pyb0 = lx2<M>(bi01);
    v2f pxa2 = lx2<M>(ae23);  v2f pxb2 = lx2<M>(be23);
    v2f pya2 = lx2<M>(ai23);  v2f pyb2 = lx2<M>(bi23);
    v2f nae0 = u0*ae01 - u1*ai01 + u2*pxa0 - u3*pya0;
    v2f nbe0 = u0*be01 - u1*bi01 + u2*pxb0 - u3*pyb0;
    v2f nai0 = u0*ai01 + u1*ae01 + u2*pya0 + u3*pxa0;
    v2f nbi0 = u0*bi01 + u1*be01 + u2*pyb0 + u3*pxb0;
    v2f nae2 = u0*ae23 - u1*ai23 + u2*pxa2 - u3*pya2;
    v2f nbe2 = u0*be23 - u1*bi23 + u2*pxb2 - u3*pyb2;
    v2f nai2 = u0*ai23 + u1*ae23 + u2*pya2 + u3*pxa2;
    v2f nbi2 = u0*bi23 + u1*be23 + u2*pyb2 + u3*pxb2;
    ae01 = nae0; be01 = nbe0; ai01 = nai0; bi01 = nbi0;
    ae23 = nae2; be23 = nbe2; ai23 = nai2; bi23 = nbi2;
}

__global__ __launch_bounds__(256, 1) void qlstm_kernel(Args a) {
    const int b0   = blockIdx.x * 2, b1 = b0 + 1;
    const int tid  = threadIdx.x;
    const int lane = tid & 63;
    const int wv   = tid >> 6;

    __shared__ float Ax[2][TT][32];
    __shared__ __align__(16) float hH[2][16][HID];
    __shared__ __align__(16) float4 uab[4][2][8];
    __shared__ __align__(16) float expL[2][32];

    const int a_ang = tid >> 3, p = tid & 7;
    const int g_ang = a_ang >> 3, q_ang = a_ang & 7;
    v2f whr2[8][2];
    {
        const float* Wg = a.W[g_ang] + q_ang * CD + IND;
#pragma unroll
        for (int k = 0; k < 8; ++k) {
            int base = p * 32 + ((4 * (k + p)) & 31);
            whr2[k][0] = pk(Wg[base + 0], Wg[base + 1]);
            whr2[k][1] = pk(Wg[base + 2], Wg[base + 3]);
        }
    }
    v2f ur2a[8], ur2b[8], cb2a, cb2b;
#pragma unroll
    for (int k = 0; k < 8; ++k) {
        ur2a[k] = pk(a.Uo[0][tid * 8 + k], a.Uo[1][tid * 8 + k]);
        ur2b[k] = pk(a.Uo[2][tid * 8 + k], a.Uo[3][tid * 8 + k]);
    }
    cb2a = pk(a.cb[0][tid], a.cb[1][tid]);
    cb2b = pk(a.cb[2][tid], a.cb[3][tid]);

    if (tid < 64) {
        int g = tid >> 4, d = (tid >> 3) & 1, q = tid & 7;
        const float* qp = a.qp[g] + q * 6 + d * 3;
        float s0, c0, s1, c1, s2, c2;
        sincosf(0.5f * qp[0], &s0, &c0);
        sincosf(0.5f * qp[1], &s1, &c1);
        sincosf(0.5f * qp[2], &s2, &c2);
        C2 aX{c0, 0.f}, bX{0.f, -s0};
        C2 aY{c1, 0.f}, bY{-s1, 0.f};
        C2 aB = csub(cmul(aY, aX), cmul(bY, conjc(bX)));
        C2 bB = cadd(cmul(aY, bX), cmul(bY, conjc(aX)));
        C2 aZ{c2, -s2};
        C2 al = cmul(aZ, aB), be = cmul(aZ, bB);
        uab[g][d][q] = make_float4(al.x, al.y, be.x, be.y);
    }

    for (int rep = 0; rep < 16; ++rep) {
        int idx = rep * 256 + tid;
        int s = idx >> 11, t = (idx >> 5) & 63, aa = idx & 31;
        int gg = aa >> 3, qq = aa & 7;
        const float4* w4 = (const float4*)(a.W[gg] + qq * CD);
        const float4* x4 = (const float4*)(a.x + (size_t)(t * BB + b0 + s) * IND);
        float acc = a.bb[gg][qq];
        for (int e = 0; e < IND / 4; ++e) {
            float4 xv = x4[e], wvv = w4[e];
            acc += xv.x * wvv.x + xv.y * wvv.y + xv.z * wvv.z + xv.w * wvv.w;
        }
        Ax[s][t][aa] = acc;
    }

    hH[0][15][tid] = 0.f;
    hH[1][15][tid] = 0.f;
    float creg0 = 0.f, h0 = 0.f, creg1 = 0.f, h1 = 0.f;
    __syncthreads();

    v2f pA[8], pB[8], pC[8], pD[8];
#pragma unroll
    for (int q = 0; q < 8; ++q) {
        float4 u = uab[wv][0][q];
        float ax = rfl(u.x), ay = rfl(u.y), bx = rfl(u.z), by = rfl(u.w);
        pA[q] = pk(ax, -bx);
        pB[q] = pk(by, -ay);
        pC[q] = pk(ay, by);
        pD[q] = pk(-bx, -ax);
    }
    float gA[6][4];
#pragma unroll
    for (int qi = 0; qi < 6; ++qi) {
        float4 u = uab[wv][1][qi + 2];
        bool bit = (lane >> (5 - qi)) & 1;
        gA[qi][0] = u.x;
        gA[qi][1] = bit ? -u.y : u.y;
        gA[qi][2] = bit ? -u.z : u.z;
        gA[qi][3] = u.w;
    }
    float q0ax, q0ay, q0bx, q0by, q1ax, q1by;
    v2f q1aym, q1ayp, q1bxm;
    {
        float4 u0 = uab[wv][1][0], u1 = uab[wv][1][1];
        q0ax = rfl(u0.x); q0ay = rfl(u0.y); q0bx = rfl(u0.z); q0by = rfl(u0.w);
        q1ax = rfl(u1.x); q1by = rfl(u1.w);
        float ay = rfl(u1.y), bx = rfl(u1.z);
        q1aym = pk(-ay, ay);
        q1ayp = pk(ay, -ay);
        q1bxm = pk(bx, -bx);
    }

    const bool st3 = ((lane >> 4) ^ (lane >> 5)) & 1;
    const bool st4 = ((lane >> 3) ^ (lane >> 4)) & 1;
    const bool st5 = ((lane >> 2) ^ (lane >> 3)) & 1;
    const bool st6 = ((lane >> 1) ^ (lane >> 2)) & 1;
    const bool st7 = (lane ^ (lane >> 1)) & 1;
    const bool sp2 = (lane >> 5) & 1;
    const bool sp7 = lane & 1;

    unsigned sg0, sg2, sg3, sg4, sg5, sg6, sg7;
    {
        auto par31 = [](int v) -> unsigned { return (unsigned)(__popc(v) & 1) << 31; };
        sg0 = par31(lane & 63);
        sg2 = par31(lane & 32);
        sg3 = par31(lane & 48);
        sg4 = par31(lane & 56);
        sg5 = par31(lane & 60);
        sg6 = par31(lane & 62);
        sg7 = sg0;
    }

    for (int t = 0; t < TT; ++t) {
        // ---- angle stage, both samples interleaved ----
        const int rowPrev = (t + 15) & 15;
        const float* hrow0 = hH[0][rowPrev];
        const float* hrow1 = hH[1][rowPrev];
        v2f acc2_0 = pk(0.f, 0.f), acc2_1 = pk(0.f, 0.f);
#pragma unroll
        for (int k = 0; k < 8; ++k) {
            int base = p * 32 + ((4 * (k + p)) & 31);
            const float4 hv0 = *reinterpret_cast<const float4*>(&hrow0[base]);
            const float4 hv1 = *reinterpret_cast<const float4*>(&hrow1[base]);
            acc2_0 = acc2_0 + pk(hv0.x, hv0.y) * whr2[k][0] + pk(hv0.z, hv0.w) * whr2[k][1];
            acc2_1 = acc2_1 + pk(hv1.x, hv1.y) * whr2[k][0] + pk(hv1.z, hv1.w) * whr2[k][1];
        }
        float acc0 = acc2_0.x + acc2_0.y;
        float acc1 = acc2_1.x + acc2_1.y;
        acc0 += lx<1>(acc0);  acc1 += lx<1>(acc1);
        acc0 += lx<2>(acc0);  acc1 += lx<2>(acc1);
        acc0 += lx<4>(acc0);  acc1 += lx<4>(acc1);
        float ang0 = 0.5f * (acc0 + Ax[0][t][a_ang]);
        float ang1 = 0.5f * (acc1 + Ax[1][t][a_ang]);
        float cA0 = __cosf(ang0), sA0 = __sinf(ang0);
        float cA1 = __cosf(ang1), sA1 = __sinf(ang1);
        float cs_c0[8], cs_s0[8], cs_c1[8], cs_s1[8];
#pragma unroll
        for (int q = 0; q < 8; ++q) {
            cs_c0[q] = bcast_lane(cA0, q * 8);
            cs_s0[q] = bcast_lane(sA0, q * 8);
            cs_c1[q] = bcast_lane(cA1, q * 8);
            cs_s1[q] = bcast_lane(sA1, q * 8);
        }

        // ---- v-build, interleaved ----
        v2f Vx0[8], Vy0[8], Vx1[8], Vy1[8];
#pragma unroll
        for (int q = 0; q < 8; ++q) {
            Vx0[q] = pA[q] * cs_c0[q] + pB[q] * cs_s0[q];
            Vx1[q] = pA[q] * cs_c1[q] + pB[q] * cs_s1[q];
            Vy0[q] = pC[q] * cs_c0[q] + pD[q] * cs_s0[q];
            Vy1[q] = pC[q] * cs_c1[q] + pD[q] * cs_s1[q];
        }

        // ---- init product at M^-1(p), statements interleaved A/B ----
        v2f Ae01, Ai01, Ae23, Ai23, Be01, Bi01, Be23, Bi23;
        {
            C2 f3a{ st3 ? Vx0[3].y : Vx0[3].x, st3 ? Vy0[3].y : Vy0[3].x };
            C2 f3b{ st3 ? Vx1[3].y : Vx1[3].x, st3 ? Vy1[3].y : Vy1[3].x };
            C2 f4a{ st4 ? Vx0[4].y : Vx0[4].x, st4 ? Vy0[4].y : Vy0[4].x };
            C2 f4b{ st4 ? Vx1[4].y : Vx1[4].x, st4 ? Vy1[4].y : Vy1[4].x };
            C2 f5a{ st5 ? Vx0[5].y : Vx0[5].x, st5 ? Vy0[5].y : Vy0[5].x };
            C2 f5b{ st5 ? Vx1[5].y : Vx1[5].x, st5 ? Vy1[5].y : Vy1[5].x };
            C2 f6a{ st6 ? Vx0[6].y : Vx0[6].x, st6 ? Vy0[6].y : Vy0[6].x };
            C2 f6b{ st6 ? Vx1[6].y : Vx1[6].x, st6 ? Vy1[6].y : Vy1[6].x };
            C2 f7a{ st7 ? Vx0[7].y : Vx0[7].x, st7 ? Vy0[7].y : Vy0[7].x };
            C2 f7b{ st7 ? Vx1[7].y : Vx1[7].x, st7 ? Vy1[7].y : Vy1[7].x };
            C2 m34a = cmul(f3a, f4a);
            C2 m34b = cmul(f3b, f4b);
            C2 m56a = cmul(f5a, f6a);
            C2 m56b = cmul(f5b, f6b);
            C2 m36a = cmul(m34a, m56a);
            C2 m36b = cmul(m34b, m56b);
            C2 c5a = cmul(m36a, f7a);
            C2 c5b = cmul(m36b, f7b);
            v2f f2reA = sp2 ? swp(Vx0[2]) : Vx0[2];
            v2f f2reB = sp2 ? swp(Vx1[2]) : Vx1[2];
            v2f f2imA = sp2 ? swp(Vy0[2]) : Vy0[2];
            v2f f2imB = sp2 ? swp(Vy1[2]) : Vy1[2];
            v2f c2reA = c5a.x * f2reA - c5a.y * f2imA;
            v2f c2reB = c5b.x * f2reB - c5b.y * f2imB;
            v2f c2imA = c5a.x * f2imA + c5a.y * f2reA;
            v2f c2imB = c5b.x * f2imB + c5b.y * f2reB;
            v2f f1reA = sp7 ? swp(Vx0[1]) : Vx0[1];
            v2f f1reB = sp7 ? swp(Vx1[1]) : Vx1[1];
            v2f f1imA = sp7 ? swp(Vy0[1]) : Vy0[1];
            v2f f1imB = sp7 ? swp(Vy1[1]) : Vy1[1];
            float f0axA = sp7 ? Vx0[0].y : Vx0[0].x, f0ayA = sp7 ? Vy0[0].y : Vy0[0].x;
            float f0axB = sp7 ? Vx1[0].y : Vx1[0].x, f0ayB = sp7 ? Vy1[0].y : Vy1[0].x;
            float f0bxA = sp7 ? Vx0[0].x : Vx0[0].y, f0byA = sp7 ? Vy0[0].x : Vy0[0].y;
            float f0bxB = sp7 ? Vx1[0].x : Vx1[0].y, f0byB = sp7 ? Vy1[0].x : Vy1[0].y;
            v2f uureA = f1reA * f0axA - f1imA * f0ayA;
            v2f uureB = f1reB * f0axB - f1imB * f0ayB;
            v2f uuimA = f1reA * f0ayA + f1imA * f0axA;
            v2f uuimB = f1reB * f0ayB + f1imB * f0axB;
            v2f s1reA = swp(f1reA), s1imA = swp(f1imA);
            v2f s1reB = swp(f1reB), s1imB = swp(f1imB);
            v2f wwreA = s1reA * f0bxA - s1imA * f0byA;
            v2f wwreB = s1reB * f0bxB - s1imB * f0byB;
            v2f wwimA = s1reA * f0byA + s1imA * f0bxA;
            v2f wwimB = s1reB * f0byB + s1imB * f0bxB;
            Ae01 = c2reA * uureA - c2imA * uuimA;
            Be01 = c2reB * uureB - c2imB * uuimB;
            Ai01 = c2reA * uuimA + c2imA * uureA;
            Bi01 = c2reB * uuimB + c2imB * uureB;
            Ae23 = c2reA * wwreA - c2imA * wwimA;
            Be23 = c2reB * wwreB - c2imB * wwimB;
            Ai23 = c2reA * wwimA + c2imA * wwreA;
            Bi23 = c2reB * wwimB + c2imB * wwreB;
        }

        // ---- d=1 reg-gates, interleaved ----
        {
            v2f nAe01 = q0ax*Ae01 - q0ay*Ai01 + q0bx*Ae23 - q0by*Ai23;
            v2f nBe01 = q0ax*Be01 - q0ay*Bi01 + q0bx*Be23 - q0by*Bi23;
            v2f nAi01 = q0ax*Ai01 + q0ay*Ae01 + q0bx*Ai23 + q0by*Ae23;
            v2f nBi01 = q0ax*Bi01 + q0ay*Be01 + q0bx*Bi23 + q0by*Be23;
            v2f nAe23 = -q0bx*Ae01 - q0by*Ai01 + q0ax*Ae23 + q0ay*Ai23;
            v2f nBe23 = -q0bx*Be01 - q0by*Bi01 + q0ax*Be23 + q0ay*Bi23;
            v2f nAi23 = -q0bx*Ai01 + q0by*Ae01 + q0ax*Ai23 - q0ay*Ae23;
            v2f nBi23 = -q0bx*Bi01 + q0by*Be01 + q0ax*Bi23 - q0ay*Be23;
            Ae01 = nAe01; Be01 = nBe01; Ai01 = nAi01; Bi01 = nBi01;
            Ae23 = nAe23; Be23 = nBe23; Ai23 = nAi23; Bi23 = nBi23;
        }
        {
            v2f sAe01 = swp(Ae01), sAi01 = swp(Ai01);
            v2f sBe01 = swp(Be01), sBi01 = swp(Bi01);
            v2f sAe23 = swp(Ae23), sAi23 = swp(Ai23);
            v2f sBe23 = swp(Be23), sBi23 = swp(Bi23);
            v2f nAe01 = q1ax*Ae01 + q1aym*Ai01 + q1bxm*sAe01 - q1by*sAi01;
            v2f nBe01 = q1ax*Be01 + q1aym*Bi01 + q1bxm*sBe01 - q1by*sBi01;
            v2f nAi01 = q1ax*Ai01 + q1ayp*Ae01 + q1bxm*sAi01 + q1by*sAe01;
            v2f nBi01 = q1ax*Bi01 + q1ayp*Be01 + q1bxm*sBi01 + q1by*sBe01;
            v2f nAe23 = q1ax*Ae23 + q1aym*Ai23 + q1bxm*sAe23 - q1by*sAi23;
            v2f nBe23 = q1ax*Be23 + q1aym*Bi23 + q1bxm*sBe23 - q1by*sBi23;
            v2f nAi23 = q1ax*Ai23 + q1ayp*Ae23 + q1bxm*sAi23 + q1by*sAe23;
            v2f nBi23 = q1ax*Bi23 + q1ayp*Be23 + q1bxm*sBi23 + q1by*sBe23;
            Ae01 = nAe01; Be01 = nBe01; Ai01 = nAi01; Bi01 = nBi01;
            Ae23 = nAe23; Be23 = nBe23; Ai23 = nAi23; Bi23 = nBi23;
        }
        // ---- d=1 lane-gates, fused dual-sample ----
        gate_lane_pk2<32>(Ae01, Ai01, Ae23, Ai23, Be01, Bi01, Be23, Bi23,
                          gA[0][0], gA[0][1], gA[0][2], gA[0][3]);
        gate_lane_pk2<16>(Ae01, Ai01, Ae23, Ai23, Be01, Bi01, Be23, Bi23,
                          gA[1][0], gA[1][1], gA[1][2], gA[1][3]);
        gate_lane_pk2< 8>(Ae01, Ai01, Ae23, Ai23, Be01, Bi01, Be23, Bi23,
                          gA[2][0], gA[2][1], gA[2][2], gA[2][3]);
        gate_lane_pk2< 4>(Ae01, Ai01, Ae23, Ai23, Be01, Bi01, Be23, Bi23,
                          gA[3][0], gA[3][1], gA[3][2], gA[3][3]);
        gate_lane_pk2< 2>(Ae01, Ai01, Ae23, Ai23, Be01, Bi01, Be23, Bi23,
                          gA[4][0], gA[4][1], gA[4][2], gA[4][3]);
        gate_lane_pk2< 1>(Ae01, Ai01, Ae23, Ai23, Be01, Bi01, Be23, Bi23,
                          gA[5][0], gA[5][1], gA[5][2], gA[5][3]);

        // ---- butterfly, fused dual-sample ----
        v2f zA0, zB0, zC0, zD0, zA1, zB1, zC1, zD1;
        {
            v2f pr01a = Ae01 * Ae01 + Ai01 * Ai01;
            v2f pr01b = Be01 * Be01 + Bi01 * Bi01;
            v2f pr23a = Ae23 * Ae23 + Ai23 * Ai23;
            v2f pr23b = Be23 * Be23 + Bi23 * Bi23;
            float Bca = pr01a.x - pr01a.y + pr23a.x - pr23a.y;
            float Bcb = pr01b.x - pr01b.y + pr23b.x - pr23b.y;
            float Dca = pr01a.x - pr01a.y - pr23a.x + pr23a.y;
            float Dcb = pr01b.x - pr01b.y - pr23b.x + pr23b.y;
            zA0 = pk(sgnx(Bca, sg0), Dca);
            zA1 = pk(sgnx(Bcb, sg0), Dcb);
            zB0 = pk(sgnx(Dca, sg2), sgnx(Dca, sg3));
            zB1 = pk(sgnx(Dcb, sg2), sgnx(Dcb, sg3));
            zC0 = pk(sgnx(Dca, sg4), sgnx(Dca, sg5));
            zC1 = pk(sgnx(Dcb, sg4), sgnx(Dcb, sg5));
            zD0 = pk(sgnx(Dca, sg6), sgnx(Dca, sg7));
            zD1 = pk(sgnx(Dcb, sg6), sgnx(Dcb, sg7));
            zA0 = zA0 + lx2<1>(zA0);  zA1 = zA1 + lx2<1>(zA1);
            zB0 = zB0 + lx2<1>(zB0);  zB1 = zB1 + lx2<1>(zB1);
            zC0 = zC0 + lx2<1>(zC0);  zC1 = zC1 + lx2<1>(zC1);
            zD0 = zD0 + lx2<1>(zD0);  zD1 = zD1 + lx2<1>(zD1);
            zA0 = zA0 + lx2<2>(zA0);  zA1 = zA1 + lx2<2>(zA1);
            zB0 = zB0 + lx2<2>(zB0);  zB1 = zB1 + lx2<2>(zB1);
            zC0 = zC0 + lx2<2>(zC0);  zC1 = zC1 + lx2<2>(zC1);
            zD0 = zD0 + lx2<2>(zD0);  zD1 = zD1 + lx2<2>(zD1);
            zA0 = zA0 + lx2<4>(zA0);  zA1 = zA1 + lx2<4>(zA1);
            zB0 = zB0 + lx2<4>(zB0);  zB1 = zB1 + lx2<4>(zB1);
            zC0 = zC0 + lx2<4>(zC0);  zC1 = zC1 + lx2<4>(zC1);
            zD0 = zD0 + lx2<4>(zD0);  zD1 = zD1 + lx2<4>(zD1);
            zA0 = zA0 + lx2<8>(zA0);  zA1 = zA1 + lx2<8>(zA1);
            zB0 = zB0 + lx2<8>(zB0);  zB1 = zB1 + lx2<8>(zB1);
            zC0 = zC0 + lx2<8>(zC0);  zC1 = zC1 + lx2<8>(zC1);
            zD0 = zD0 + lx2<8>(zD0);  zD1 = zD1 + lx2<8>(zD1);
            zA0 = zA0 + lx2<16>(zA0); zA1 = zA1 + lx2<16>(zA1);
            zB0 = zB0 + lx2<16>(zB0); zB1 = zB1 + lx2<16>(zB1);
            zC0 = zC0 + lx2<16>(zC0); zC1 = zC1 + lx2<16>(zC1);
            zD0 = zD0 + lx2<16>(zD0); zD1 = zD1 + lx2<16>(zD1);
            zA0 = zA0 + lx2<32>(zA0); zA1 = zA1 + lx2<32>(zA1);
            zB0 = zB0 + lx2<32>(zB0); zB1 = zB1 + lx2<32>(zB1);
            zC0 = zC0 + lx2<32>(zC0); zC1 = zC1 + lx2<32>(zC1);
            zD0 = zD0 + lx2<32>(zD0); zD1 = zD1 + lx2<32>(zD1);
        }

        if (lane == 0) {
            expL[0][0*4 + wv] = zA0.x; expL[0][1*4 + wv] = zA0.y;
            expL[0][2*4 + wv] = zB0.x; expL[0][3*4 + wv] = zB0.y;
            expL[0][4*4 + wv] = zC0.x; expL[0][5*4 + wv] = zC0.y;
            expL[0][6*4 + wv] = zD0.x; expL[0][7*4 + wv] = zD0.y;
        }
        if (lane == 1) {
            expL[1][0*4 + wv] = zA1.x; expL[1][1*4 + wv] = zA1.y;
            expL[1][2*4 + wv] = zB1.x; expL[1][3*4 + wv] = zB1.y;
            expL[1][4*4 + wv] = zC1.x; expL[1][5*4 + wv] = zC1.y;
            expL[1][6*4 + wv] = zD1.x; expL[1][7*4 + wv] = zD1.y;
        }
        __syncthreads();

        // ---- output projection + pointwise, interleaved ----
        {
            const float4* eL0 = (const float4*)expL[0];
            const float4* eL1 = (const float4*)expL[1];
            v2f og2a0 = cb2a, og2b0 = cb2b;
            v2f og2a1 = cb2a, og2b1 = cb2b;
#pragma unroll
            for (int k = 0; k < 8; ++k) {
                float4 e40 = eL0[k];
                float4 e41 = eL1[k];
                og2a0 = og2a0 + pk(e40.x, e40.y) * ur2a[k];
                og2a1 = og2a1 + pk(e41.x, e41.y) * ur2a[k];
                og2b0 = og2b0 + pk(e40.z, e40.w) * ur2b[k];
                og2b1 = og2b1 + pk(e41.z, e41.w) * ur2b[k];
            }
            float fg0 = sigm(og2a0.x);
            float fg1 = sigm(og2a1.x);
            float ig0 = sigm(og2a0.y);
            float ig1 = sigm(og2a1.y);
            float gg0 = tanh_fast(og2b0.x);
            float gg1 = tanh_fast(og2b1.x);
            float oo0 = sigm(og2b0.y);
            float oo1 = sigm(og2b1.y);
            creg0 = fg0 * creg0 + ig0 * gg0;
            creg1 = fg1 * creg1 + ig1 * gg1;
            h0 = oo0 * tanh_fast(creg0);
            h1 = oo1 * tanh_fast(creg1);
        }

        hH[0][t & 15][tid] = h0;
        hH[1][t & 15][tid] = h1;
        if ((t & 15) == 15) {
            int t0 = t - 15;
#pragma unroll
            for (int r = 0; r < 16; ++r) {
                a.out[(size_t)((t0 + r) * BB + b0) * HID + tid] = hH[0][r][tid];
                a.out[(size_t)((t0 + r) * BB + b1) * HID + tid] = hH[1][r][tid];
            }
        }
        __syncthreads();
    }

    a.out[(size_t)TT * BB * HID + (size_t)b0 * HID + tid] = h0;
    a.out[(size_t)TT * BB * HID + (size_t)b1 * HID + tid] = h1;
    a.out[(size_t)TT * BB * HID + (size_t)BB * HID + (size_t)b0 * HID + tid] = creg0;
    a.out[(size_t)TT * BB * HID + (size_t)BB * HID + (size_t)b1 * HID + tid] = creg1;
}

extern "C" void kernel_launch(void* const* d_in, const int* in_sizes, int n_in,
                              void* d_out, int out_size, void* d_ws, size_t ws_size,
                              hipStream_t stream) {
    (void)in_sizes; (void)n_in; (void)out_size; (void)d_ws; (void)ws_size;
    Args ar;
    ar.x = (const float*)d_in[0];
    for (int g = 0; g < 4; ++g) {
        ar.W[g]  = (const float*)d_in[1 + 5 * g];
        ar.bb[g] = (const float*)d_in[2 + 5 * g];
        ar.qp[g] = (const float*)d_in[3 + 5 * g];
        ar.Uo[g] = (const float*)d_in[4 + 5 * g];
        ar.cb[g] = (const float*)d_in[5 + 5 * g];
    }
    ar.out = (float*)d_out;
    qlstm_kernel<<<dim3(BB / 2), dim3(256), 0, stream>>>(ar);
}

// Round 15
// 244.126 us; speedup vs baseline: 1.0499x; 1.0077x over previous
//
#include <hip/hip_runtime.h>
#include <math.h>

#define BB   128
#define TT   64
#define IND  128
#define HID  256
#define CD   384   // comb dim = IND + HID

typedef float v2f __attribute__((ext_vector_type(2)));
typedef float v4f __attribute__((ext_vector_type(4)));
typedef int   v2i __attribute__((ext_vector_type(2)));
typedef int   v4i __attribute__((ext_vector_type(4)));

struct C2 { float x, y; };
__device__ __forceinline__ C2 cmul(C2 a, C2 b) { return {a.x*b.x - a.y*b.y, a.x*b.y + a.y*b.x}; }
__device__ __forceinline__ C2 cadd(C2 a, C2 b) { return {a.x + b.x, a.y + b.y}; }
__device__ __forceinline__ C2 csub(C2 a, C2 b) { return {a.x - b.x, a.y - b.y}; }
__device__ __forceinline__ C2 conjc(C2 a) { return {a.x, -a.y}; }

__device__ __forceinline__ v2f pk(float a, float b) { v2f r; r.x = a; r.y = b; return r; }
__device__ __forceinline__ v4f pk4(float a, float b, float c, float d) {
    v4f r; r.x = a; r.y = b; r.z = c; r.w = d; return r;
}
__device__ __forceinline__ v2f swp(v2f v) { return __builtin_shufflevector(v, v, 1, 0); }
__device__ __forceinline__ v4f swp4(v4f v) { return __builtin_shufflevector(v, v, 1, 0, 3, 2); }
__device__ __forceinline__ v4f cat2(v2f a, v2f b) { return __builtin_shufflevector(a, b, 0, 1, 2, 3); }
__device__ __forceinline__ v4f spread2(v2f v) { return __builtin_shufflevector(v, v, 0, 0, 1, 1); }
__device__ __forceinline__ v2f even4(v4f v) { return __builtin_shufflevector(v, v, 0, 2); }
__device__ __forceinline__ v2f odd4(v4f v) { return __builtin_shufflevector(v, v, 1, 3); }
__device__ __forceinline__ v4f vxor4(v4f v, v4i m) {
    v4i iv = __builtin_bit_cast(v4i, v) ^ m;
    return __builtin_bit_cast(v4f, iv);
}
__device__ __forceinline__ v2f vxor2(v2f v, v2i m) {
    v2i iv = __builtin_bit_cast(v2i, v) ^ m;
    return __builtin_bit_cast(v2f, iv);
}

struct Args {
    const float* x;
    const float* W[4];
    const float* bb[4];
    const float* qp[4];
    const float* Uo[4];
    const float* cb[4];
    float* out;
};

template<int CTRL>
__device__ __forceinline__ int dppmv(int v) {
    return __builtin_amdgcn_update_dpp(v, v, CTRL, 0xF, 0xF, false);
}

// Lane-xor exchange (R9-R12 proven, all-VALU).
template<int M>
__device__ __forceinline__ float lx(float v) {
    int i = __float_as_int(v);
    if constexpr (M == 1)
        return __int_as_float(dppmv<0xB1>(i));
    else if constexpr (M == 2)
        return __int_as_float(dppmv<0x4E>(i));
    else if constexpr (M == 4) {
        int a = dppmv<0x104>(i);
        int b = dppmv<0x114>(i);
        return __int_as_float((threadIdx.x & 4) ? b : a);
    } else if constexpr (M == 8)
        return __int_as_float(dppmv<0x128>(i));
    else if constexpr (M == 16) {
#if __has_builtin(__builtin_amdgcn_permlane16_swap)
        auto r = __builtin_amdgcn_permlane16_swap(i, i, false, false);
        return __int_as_float((threadIdx.x & 16) ? r[0] : r[1]);
#else
        return __int_as_float(__builtin_amdgcn_ds_swizzle(i, 0x401F));
#endif
    } else {
#if __has_builtin(__builtin_amdgcn_permlane32_swap)
        auto r = __builtin_amdgcn_permlane32_swap(i, i, false, false);
        return __int_as_float((threadIdx.x & 32) ? r[0] : r[1]);
#else
        return __shfl_xor(v, 32);
#endif
    }
}
template<int M>
__device__ __forceinline__ v2f lx2(v2f v) {
    return pk(lx<M>(v.x), lx<M>(v.y));
}
template<int M>
__device__ __forceinline__ v4f lx4(v4f v) {
    return pk4(lx<M>(v.x), lx<M>(v.y), lx<M>(v.z), lx<M>(v.w));
}

__device__ __forceinline__ float rfl(float v) {
    return __int_as_float(__builtin_amdgcn_readfirstlane(__float_as_int(v)));
}
__device__ __forceinline__ float bcast_lane(float v, int srclane) {
    return __int_as_float(__builtin_amdgcn_readlane(__float_as_int(v), srclane));
}
__device__ __forceinline__ float sigm(float x) {
    return __builtin_amdgcn_rcpf(1.f + __expf(-x));
}
__device__ __forceinline__ float tanh_fast(float x) {
    float e = __expf(2.f * x);
    return 1.f - 2.f * __builtin_amdgcn_rcpf(e + 1.f);
}

// Dual-complex (re/im packed across the two samples in v2f lanes).
struct DC { v2f re, im; };
__device__ __forceinline__ DC dmul(DC a, DC b) {
    DC r;
    r.re = a.re * b.re - a.im * b.im;
    r.im = a.re * b.im + a.im * b.re;
    return r;
}

// SU(2) lane-gate on dual-sample v4f state: the v4f ops CANNOT be split by the
// scheduler (single SSA values) -> each lowers to 2 back-to-back v_pk_fma.
// (R13/R14 lesson: two independent scalar streams get re-serialized; VGPR=196.)
template<int M>
__device__ __forceinline__ void gate_lane_pk4(v4f& Xe01, v4f& Xi01, v4f& Xe23, v4f& Xi23,
                                              float u0, float u1, float u2, float u3) {
    v4f px0 = lx4<M>(Xe01), py0 = lx4<M>(Xi01);
    v4f px2 = lx4<M>(Xe23), py2 = lx4<M>(Xi23);
    v4f ne0 = u0*Xe01 - u1*Xi01 + u2*px0 - u3*py0;
    v4f ni0 = u0*Xi01 + u1*Xe01 + u2*py0 + u3*px0;
    v4f ne2 = u0*Xe23 - u1*Xi23 + u2*px2 - u3*py2;
    v4f ni2 = u0*Xi23 + u1*Xe23 + u2*py2 + u3*px2;
    Xe01 = ne0; Xi01 = ni0; Xe23 = ne2; Xi23 = ni2;
}

__global__ __launch_bounds__(256, 1) void qlstm_kernel(Args a) {
    const int b0   = blockIdx.x * 2, b1 = b0 + 1;
    const int tid  = threadIdx.x;
    const int lane = tid & 63;
    const int wv   = tid >> 6;

    __shared__ float Ax[2][TT][32];
    __shared__ __align__(16) float hH[2][16][HID];
    __shared__ __align__(16) float4 uab[4][2][8];
    __shared__ __align__(16) float expL[2][32];

    const int a_ang = tid >> 3, p = tid & 7;
    const int g_ang = a_ang >> 3, q_ang = a_ang & 7;
    v2f whr2[8][2];
    {
        const float* Wg = a.W[g_ang] + q_ang * CD + IND;
#pragma unroll
        for (int k = 0; k < 8; ++k) {
            int base = p * 32 + ((4 * (k + p)) & 31);
            whr2[k][0] = pk(Wg[base + 0], Wg[base + 1]);
            whr2[k][1] = pk(Wg[base + 2], Wg[base + 3]);
        }
    }
    v2f ur2a[8], ur2b[8], cb2a, cb2b;
#pragma unroll
    for (int k = 0; k < 8; ++k) {
        ur2a[k] = pk(a.Uo[0][tid * 8 + k], a.Uo[1][tid * 8 + k]);
        ur2b[k] = pk(a.Uo[2][tid * 8 + k], a.Uo[3][tid * 8 + k]);
    }
    cb2a = pk(a.cb[0][tid], a.cb[1][tid]);
    cb2b = pk(a.cb[2][tid], a.cb[3][tid]);

    if (tid < 64) {
        int g = tid >> 4, d = (tid >> 3) & 1, q = tid & 7;
        const float* qp = a.qp[g] + q * 6 + d * 3;
        float s0, c0, s1, c1, s2, c2;
        sincosf(0.5f * qp[0], &s0, &c0);
        sincosf(0.5f * qp[1], &s1, &c1);
        sincosf(0.5f * qp[2], &s2, &c2);
        C2 aX{c0, 0.f}, bX{0.f, -s0};
        C2 aY{c1, 0.f}, bY{-s1, 0.f};
        C2 aB = csub(cmul(aY, aX), cmul(bY, conjc(bX)));
        C2 bB = cadd(cmul(aY, bX), cmul(bY, conjc(aX)));
        C2 aZ{c2, -s2};
        C2 al = cmul(aZ, aB), be = cmul(aZ, bB);
        uab[g][d][q] = make_float4(al.x, al.y, be.x, be.y);
    }

    for (int rep = 0; rep < 16; ++rep) {
        int idx = rep * 256 + tid;
        int s = idx >> 11, t = (idx >> 5) & 63, aa = idx & 31;
        int gg = aa >> 3, qq = aa & 7;
        const float4* w4 = (const float4*)(a.W[gg] + qq * CD);
        const float4* x4 = (const float4*)(a.x + (size_t)(t * BB + b0 + s) * IND);
        float acc = a.bb[gg][qq];
        for (int e = 0; e < IND / 4; ++e) {
            float4 xv = x4[e], wvv = w4[e];
            acc += xv.x * wvv.x + xv.y * wvv.y + xv.z * wvv.z + xv.w * wvv.w;
        }
        Ax[s][t][aa] = acc;
    }

    hH[0][15][tid] = 0.f;
    hH[1][15][tid] = 0.f;
    float creg0 = 0.f, h0 = 0.f, creg1 = 0.f, h1 = 0.f;
    __syncthreads();

    v2f pA[8], pB[8], pC[8], pD[8];
#pragma unroll
    for (int q = 0; q < 8; ++q) {
        float4 u = uab[wv][0][q];
        float ax = rfl(u.x), ay = rfl(u.y), bx = rfl(u.z), by = rfl(u.w);
        pA[q] = pk(ax, -bx);
        pB[q] = pk(by, -ay);
        pC[q] = pk(ay, by);
        pD[q] = pk(-bx, -ax);
    }
    float gA[6][4];
#pragma unroll
    for (int qi = 0; qi < 6; ++qi) {
        float4 u = uab[wv][1][qi + 2];
        bool bit = (lane >> (5 - qi)) & 1;
        gA[qi][0] = u.x;
        gA[qi][1] = bit ? -u.y : u.y;
        gA[qi][2] = bit ? -u.z : u.z;
        gA[qi][3] = u.w;
    }
    float q0ax, q0ay, q0bx, q0by, q1ax, q1by;
    v4f q1aym4, q1ayp4, q1bxm4;
    {
        float4 u0 = uab[wv][1][0], u1 = uab[wv][1][1];
        q0ax = rfl(u0.x); q0ay = rfl(u0.y); q0bx = rfl(u0.z); q0by = rfl(u0.w);
        q1ax = rfl(u1.x); q1by = rfl(u1.w);
        float ay = rfl(u1.y), bx = rfl(u1.z);
        q1aym4 = pk4(-ay, ay, -ay, ay);
        q1ayp4 = pk4(ay, -ay, ay, -ay);
        q1bxm4 = pk4(bx, -bx, bx, -bx);
    }

    const bool st3 = ((lane >> 4) ^ (lane >> 5)) & 1;
    const bool st4 = ((lane >> 3) ^ (lane >> 4)) & 1;
    const bool st5 = ((lane >> 2) ^ (lane >> 3)) & 1;
    const bool st6 = ((lane >> 1) ^ (lane >> 2)) & 1;
    const bool st7 = (lane ^ (lane >> 1)) & 1;
    const bool sp2 = (lane >> 5) & 1;
    const bool sp7 = lane & 1;

    unsigned sg0, sg2, sg3, sg4, sg5, sg6, sg7;
    {
        auto par31 = [](int v) -> unsigned { return (unsigned)(__popc(v) & 1) << 31; };
        sg0 = par31(lane & 63);
        sg2 = par31(lane & 32);
        sg3 = par31(lane & 48);
        sg4 = par31(lane & 56);
        sg5 = par31(lane & 60);
        sg6 = par31(lane & 62);
        sg7 = sg0;
    }
    const v2i mA2 = { (int)sg0, (int)sg0 };
    const v4i mB4 = { (int)sg2, (int)sg3, (int)sg2, (int)sg3 };
    const v4i mC4 = { (int)sg4, (int)sg5, (int)sg4, (int)sg5 };
    const v4i mD4 = { (int)sg6, (int)sg7, (int)sg6, (int)sg7 };

    for (int t = 0; t < TT; ++t) {
        // ---- angle stage (both samples; final reduce packed) ----
        const int rowPrev = (t + 15) & 15;
        const float* hrow0 = hH[0][rowPrev];
        const float* hrow1 = hH[1][rowPrev];
        v2f acc2_0 = pk(0.f, 0.f), acc2_1 = pk(0.f, 0.f);
#pragma unroll
        for (int k = 0; k < 8; ++k) {
            int base = p * 32 + ((4 * (k + p)) & 31);
            const float4 hv0 = *reinterpret_cast<const float4*>(&hrow0[base]);
            const float4 hv1 = *reinterpret_cast<const float4*>(&hrow1[base]);
            acc2_0 = acc2_0 + pk(hv0.x, hv0.y) * whr2[k][0] + pk(hv0.z, hv0.w) * whr2[k][1];
            acc2_1 = acc2_1 + pk(hv1.x, hv1.y) * whr2[k][0] + pk(hv1.z, hv1.w) * whr2[k][1];
        }
        v2f accP = pk(acc2_0.x + acc2_0.y, acc2_1.x + acc2_1.y);
        accP = accP + lx2<1>(accP);
        accP = accP + lx2<2>(accP);
        accP = accP + lx2<4>(accP);
        v2f angP = 0.5f * (accP + pk(Ax[0][t][a_ang], Ax[1][t][a_ang]));
        float cA0 = __cosf(angP.x), sA0 = __sinf(angP.x);
        float cA1 = __cosf(angP.y), sA1 = __sinf(angP.y);
        float cs_c0[8], cs_s0[8], cs_c1[8], cs_s1[8];
#pragma unroll
        for (int q = 0; q < 8; ++q) {
            cs_c0[q] = bcast_lane(cA0, q * 8);
            cs_s0[q] = bcast_lane(sA0, q * 8);
            cs_c1[q] = bcast_lane(cA1, q * 8);
            cs_s1[q] = bcast_lane(sA1, q * 8);
        }

        // ---- v-build (independent across q; fine unfused) ----
        v2f Vx0[8], Vy0[8], Vx1[8], Vy1[8];
#pragma unroll
        for (int q = 0; q < 8; ++q) {
            Vx0[q] = pA[q] * cs_c0[q] + pB[q] * cs_s0[q];
            Vx1[q] = pA[q] * cs_c1[q] + pB[q] * cs_s1[q];
            Vy0[q] = pC[q] * cs_c0[q] + pD[q] * cs_s0[q];
            Vy1[q] = pC[q] * cs_c1[q] + pD[q] * cs_s1[q];
        }

        // ---- init product at M^-1(p): dual-complex tree (samples packed in v2f) ----
        v4f Xe01, Xi01, Xe23, Xi23;
        {
            DC f3{ pk(st3 ? Vx0[3].y : Vx0[3].x, st3 ? Vx1[3].y : Vx1[3].x),
                   pk(st3 ? Vy0[3].y : Vy0[3].x, st3 ? Vy1[3].y : Vy1[3].x) };
            DC f4{ pk(st4 ? Vx0[4].y : Vx0[4].x, st4 ? Vx1[4].y : Vx1[4].x),
                   pk(st4 ? Vy0[4].y : Vy0[4].x, st4 ? Vy1[4].y : Vy1[4].x) };
            DC f5{ pk(st5 ? Vx0[5].y : Vx0[5].x, st5 ? Vx1[5].y : Vx1[5].x),
                   pk(st5 ? Vy0[5].y : Vy0[5].x, st5 ? Vy1[5].y : Vy1[5].x) };
            DC f6{ pk(st6 ? Vx0[6].y : Vx0[6].x, st6 ? Vx1[6].y : Vx1[6].x),
                   pk(st6 ? Vy0[6].y : Vy0[6].x, st6 ? Vy1[6].y : Vy1[6].x) };
            DC f7{ pk(st7 ? Vx0[7].y : Vx0[7].x, st7 ? Vx1[7].y : Vx1[7].x),
                   pk(st7 ? Vy0[7].y : Vy0[7].x, st7 ? Vy1[7].y : Vy1[7].x) };
            DC c5 = dmul(dmul(dmul(f3, f4), dmul(f5, f6)), f7);
            v4f f2re = cat2(sp2 ? swp(Vx0[2]) : Vx0[2], sp2 ? swp(Vx1[2]) : Vx1[2]);
            v4f f2im = cat2(sp2 ? swp(Vy0[2]) : Vy0[2], sp2 ? swp(Vy1[2]) : Vy1[2]);
            v4f c5re = spread2(c5.re), c5im = spread2(c5.im);
            v4f c2re = c5re * f2re - c5im * f2im;
            v4f c2im = c5re * f2im + c5im * f2re;
            v4f f1re = cat2(sp7 ? swp(Vx0[1]) : Vx0[1], sp7 ? swp(Vx1[1]) : Vx1[1]);
            v4f f1im = cat2(sp7 ? swp(Vy0[1]) : Vy0[1], sp7 ? swp(Vy1[1]) : Vy1[1]);
            v4f f0axS = spread2(pk(sp7 ? Vx0[0].y : Vx0[0].x, sp7 ? Vx1[0].y : Vx1[0].x));
            v4f f0ayS = spread2(pk(sp7 ? Vy0[0].y : Vy0[0].x, sp7 ? Vy1[0].y : Vy1[0].x));
            v4f f0bxS = spread2(pk(sp7 ? Vx0[0].x : Vx0[0].y, sp7 ? Vx1[0].x : Vx1[0].y));
            v4f f0byS = spread2(pk(sp7 ? Vy0[0].x : Vy0[0].y, sp7 ? Vy1[0].x : Vy1[0].y));
            v4f uure = f1re * f0axS - f1im * f0ayS;
            v4f uuim = f1re * f0ayS + f1im * f0axS;
            v4f s1re = swp4(f1re), s1im = swp4(f1im);
            v4f wwre = s1re * f0bxS - s1im * f0byS;
            v4f wwim = s1re * f0byS + s1im * f0bxS;
            Xe01 = c2re * uure - c2im * uuim;
            Xi01 = c2re * uuim + c2im * uure;
            Xe23 = c2re * wwre - c2im * wwim;
            Xi23 = c2re * wwim + c2im * wwre;
        }

        // ---- d=1 reg-gates (v4f: both samples per instruction) ----
        {
            v4f ne01 = q0ax*Xe01 - q0ay*Xi01 + q0bx*Xe23 - q0by*Xi23;
            v4f ni01 = q0ax*Xi01 + q0ay*Xe01 + q0bx*Xi23 + q0by*Xe23;
            v4f ne23 = -q0bx*Xe01 - q0by*Xi01 + q0ax*Xe23 + q0ay*Xi23;
            v4f ni23 = -q0bx*Xi01 + q0by*Xe01 + q0ax*Xi23 - q0ay*Xe23;
            Xe01 = ne01; Xi01 = ni01; Xe23 = ne23; Xi23 = ni23;
        }
        {
            v4f se01 = swp4(Xe01), si01 = swp4(Xi01);
            v4f se23 = swp4(Xe23), si23 = swp4(Xi23);
            v4f ne01 = q1ax*Xe01 + q1aym4*Xi01 + q1bxm4*se01 - q1by*si01;
            v4f ni01 = q1ax*Xi01 + q1ayp4*Xe01 + q1bxm4*si01 + q1by*se01;
            v4f ne23 = q1ax*Xe23 + q1aym4*Xi23 + q1bxm4*se23 - q1by*si23;
            v4f ni23 = q1ax*Xi23 + q1ayp4*Xe23 + q1bxm4*si23 + q1by*se23;
            Xe01 = ne01; Xi01 = ni01; Xe23 = ne23; Xi23 = ni23;
        }
        // ---- d=1 lane-gates (v4f) ----
        gate_lane_pk4<32>(Xe01, Xi01, Xe23, Xi23, gA[0][0], gA[0][1], gA[0][2], gA[0][3]);
        gate_lane_pk4<16>(Xe01, Xi01, Xe23, Xi23, gA[1][0], gA[1][1], gA[1][2], gA[1][3]);
        gate_lane_pk4< 8>(Xe01, Xi01, Xe23, Xi23, gA[2][0], gA[2][1], gA[2][2], gA[2][3]);
        gate_lane_pk4< 4>(Xe01, Xi01, Xe23, Xi23, gA[3][0], gA[3][1], gA[3][2], gA[3][3]);
        gate_lane_pk4< 2>(Xe01, Xi01, Xe23, Xi23, gA[4][0], gA[4][1], gA[4][2], gA[4][3]);
        gate_lane_pk4< 1>(Xe01, Xi01, Xe23, Xi23, gA[5][0], gA[5][1], gA[5][2], gA[5][3]);

        // ---- expvals: dual-sample sign-masked Walsh butterfly (v4f) ----
        v4f pr01 = Xe01 * Xe01 + Xi01 * Xi01;
        v4f pr23 = Xe23 * Xe23 + Xi23 * Xi23;
        v2f d01 = even4(pr01) - odd4(pr01);   // per-sample pr0 - pr1
        v2f d23 = even4(pr23) - odd4(pr23);   // per-sample pr2 - pr3
        v2f Bc2 = d01 + d23;
        v2f Dc2 = d01 - d23;
        v2f Bs2 = vxor2(Bc2, mA2);
        v4f zA = __builtin_shufflevector(Bs2, Dc2, 0, 2, 1, 3);  // (B0^sg0, D0, B1^sg0, D1)
        v4f Dsp = spread2(Dc2);
        v4f zB = vxor4(Dsp, mB4);
        v4f zC = vxor4(Dsp, mC4);
        v4f zD = vxor4(Dsp, mD4);
        zA = zA + lx4<1>(zA);  zB = zB + lx4<1>(zB);  zC = zC + lx4<1>(zC);  zD = zD + lx4<1>(zD);
        zA = zA + lx4<2>(zA);  zB = zB + lx4<2>(zB);  zC = zC + lx4<2>(zC);  zD = zD + lx4<2>(zD);
        zA = zA + lx4<4>(zA);  zB = zB + lx4<4>(zB);  zC = zC + lx4<4>(zC);  zD = zD + lx4<4>(zD);
        zA = zA + lx4<8>(zA);  zB = zB + lx4<8>(zB);  zC = zC + lx4<8>(zC);  zD = zD + lx4<8>(zD);
        zA = zA + lx4<16>(zA); zB = zB + lx4<16>(zB); zC = zC + lx4<16>(zC); zD = zD + lx4<16>(zD);
        zA = zA + lx4<32>(zA); zB = zB + lx4<32>(zB); zC = zC + lx4<32>(zC); zD = zD + lx4<32>(zD);

        // all lanes hold totals: lane0 writes sample0, lane1 writes sample1
        if (lane == 0) {
            expL[0][0*4 + wv] = zA.x; expL[0][1*4 + wv] = zA.y;
            expL[0][2*4 + wv] = zB.x; expL[0][3*4 + wv] = zB.y;
            expL[0][4*4 + wv] = zC.x; expL[0][5*4 + wv] = zC.y;
            expL[0][6*4 + wv] = zD.x; expL[0][7*4 + wv] = zD.y;
        }
        if (lane == 1) {
            expL[1][0*4 + wv] = zA.z; expL[1][1*4 + wv] = zA.w;
            expL[1][2*4 + wv] = zB.z; expL[1][3*4 + wv] = zB.w;
            expL[1][4*4 + wv] = zC.z; expL[1][5*4 + wv] = zC.w;
            expL[1][6*4 + wv] = zD.z; expL[1][7*4 + wv] = zD.w;
        }
        __syncthreads();

        // ---- output projection + pointwise (short; both samples in one loop) ----
        {
            const float4* eL0 = (const float4*)expL[0];
            const float4* eL1 = (const float4*)expL[1];
            v2f og2a0 = cb2a, og2b0 = cb2b;
            v2f og2a1 = cb2a, og2b1 = cb2b;
#pragma unroll
            for (int k = 0; k < 8; ++k) {
                float4 e40 = eL0[k];
                float4 e41 = eL1[k];
                og2a0 = og2a0 + pk(e40.x, e40.y) * ur2a[k];
                og2a1 = og2a1 + pk(e41.x, e41.y) * ur2a[k];
                og2b0 = og2b0 + pk(e40.z, e40.w) * ur2b[k];
                og2b1 = og2b1 + pk(e41.z, e41.w) * ur2b[k];
            }
            float fg0 = sigm(og2a0.x);
            float fg1 = sigm(og2a1.x);
            float ig0 = sigm(og2a0.y);
            float ig1 = sigm(og2a1.y);
            float gg0 = tanh_fast(og2b0.x);
            float gg1 = tanh_fast(og2b1.x);
            float oo0 = sigm(og2b0.y);
            float oo1 = sigm(og2b1.y);
            creg0 = fg0 * creg0 + ig0 * gg0;
            creg1 = fg1 * creg1 + ig1 * gg1;
            h0 = oo0 * tanh_fast(creg0);
            h1 = oo1 * tanh_fast(creg1);
        }

        hH[0][t & 15][tid] = h0;
        hH[1][t & 15][tid] = h1;
        if ((t & 15) == 15) {
            int t0 = t - 15;
#pragma unroll
            for (int r = 0; r < 16; ++r) {
                a.out[(size_t)((t0 + r) * BB + b0) * HID + tid] = hH[0][r][tid];
                a.out[(size_t)((t0 + r) * BB + b1) * HID + tid] = hH[1][r][tid];
            }
        }
        __syncthreads();
    }

    a.out[(size_t)TT * BB * HID + (size_t)b0 * HID + tid] = h0;
    a.out[(size_t)TT * BB * HID + (size_t)b1 * HID + tid] = h1;
    a.out[(size_t)TT * BB * HID + (size_t)BB * HID + (size_t)b0 * HID + tid] = creg0;
    a.out[(size_t)TT * BB * HID + (size_t)BB * HID + (size_t)b1 * HID + tid] = creg1;
}

extern "C" void kernel_launch(void* const* d_in, const int* in_sizes, int n_in,
                              void* d_out, int out_size, void* d_ws, size_t ws_size,
                              hipStream_t stream) {
    (void)in_sizes; (void)n_in; (void)out_size; (void)d_ws; (void)ws_size;
    Args ar;
    ar.x = (const float*)d_in[0];
    for (int g = 0; g < 4; ++g) {
        ar.W[g]  = (const float*)d_in[1 + 5 * g];
        ar.bb[g] = (const float*)d_in[2 + 5 * g];
        ar.qp[g] = (const float*)d_in[3 + 5 * g];
        ar.Uo[g] = (const float*)d_in[4 + 5 * g];
        ar.cb[g] = (const float*)d_in[5 + 5 * g];
    }
    ar.out = (float*)d_out;
    qlstm_kernel<<<dim3(BB / 2), dim3(256), 0, stream>>>(ar);
}

// Round 16
// 131.525 us; speedup vs baseline: 1.9487x; 1.8561x over previous
//
#include <hip/hip_runtime.h>
#include <math.h>

#define BB   128
#define TT   64
#define IND  128
#define HID  256
#define CD   384   // comb dim = IND + HID

typedef float v2f __attribute__((ext_vector_type(2)));

struct C2 { float x, y; };
__device__ __forceinline__ C2 cmul(C2 a, C2 b) { return {a.x*b.x - a.y*b.y, a.x*b.y + a.y*b.x}; }
__device__ __forceinline__ C2 cadd(C2 a, C2 b) { return {a.x + b.x, a.y + b.y}; }
__device__ __forceinline__ C2 csub(C2 a, C2 b) { return {a.x - b.x, a.y - b.y}; }
__device__ __forceinline__ C2 conjc(C2 a) { return {a.x, -a.y}; }

__device__ __forceinline__ v2f pk(float a, float b) { v2f r; r.x = a; r.y = b; return r; }
__device__ __forceinline__ v2f swp(v2f v) { return __builtin_shufflevector(v, v, 1, 0); }

struct Args {
    const float* x;
    const float* W[4];
    const float* bb[4];
    const float* qp[4];
    const float* Uo[4];
    const float* cb[4];
    float* out;
};

template<int CTRL>
__device__ __forceinline__ int dppmv(int v) {
    return __builtin_amdgcn_update_dpp(v, v, CTRL, 0xF, 0xF, false);
}

// Lane-xor exchange (R9-R12 proven, all-VALU).
template<int M>
__device__ __forceinline__ float lx(float v) {
    int i = __float_as_int(v);
    if constexpr (M == 1)
        return __int_as_float(dppmv<0xB1>(i));            // quad_perm [1,0,3,2]
    else if constexpr (M == 2)
        return __int_as_float(dppmv<0x4E>(i));            // quad_perm [2,3,0,1]
    else if constexpr (M == 4) {
        int a = dppmv<0x104>(i);                          // row_shl:4
        int b = dppmv<0x114>(i);                          // row_shr:4
        return __int_as_float((threadIdx.x & 4) ? b : a);
    } else if constexpr (M == 8)
        return __int_as_float(dppmv<0x128>(i));           // row_ror:8 == xor8
    else if constexpr (M == 16) {
#if __has_builtin(__builtin_amdgcn_permlane16_swap)
        auto r = __builtin_amdgcn_permlane16_swap(i, i, false, false);
        return __int_as_float((threadIdx.x & 16) ? r[0] : r[1]);
#else
        return __int_as_float(__builtin_amdgcn_ds_swizzle(i, 0x401F));
#endif
    } else {
#if __has_builtin(__builtin_amdgcn_permlane32_swap)
        auto r = __builtin_amdgcn_permlane32_swap(i, i, false, false);
        return __int_as_float((threadIdx.x & 32) ? r[0] : r[1]);
#else
        return __shfl_xor(v, 32);
#endif
    }
}
template<int M>
__device__ __forceinline__ v2f lx2(v2f v) {
    return pk(lx<M>(v.x), lx<M>(v.y));
}

__device__ __forceinline__ float rfl(float v) {
    return __int_as_float(__builtin_amdgcn_readfirstlane(__float_as_int(v)));
}
__device__ __forceinline__ float bcast_lane(float v, int srclane) {
    return __int_as_float(__builtin_amdgcn_readlane(__float_as_int(v), srclane));
}
__device__ __forceinline__ float sigm(float x) {
    return __builtin_amdgcn_rcpf(1.f + __expf(-x));
}
__device__ __forceinline__ float tanh_fast(float x) {
    float e = __expf(2.f * x);
    return 1.f - 2.f * __builtin_amdgcn_rcpf(e + 1.f);
}
__device__ __forceinline__ float sgnx(float v, unsigned m) {
    return __int_as_float(__float_as_int(v) ^ (int)m);
}

// Packed SU(2) lane-gate on both reg-pairs; u0..u3 per-lane scalars (splat-broadcast).
template<int M>
__device__ __forceinline__ void gate_lane_pk(v2f& xe01, v2f& xi01, v2f& xe23, v2f& xi23,
                                             float u0, float u1, float u2, float u3) {
    v2f px0 = lx2<M>(xe01), py0 = lx2<M>(xi01);
    v2f px2 = lx2<M>(xe23), py2 = lx2<M>(xi23);
    v2f ne0 = u0*xe01 - u1*xi01 + u2*px0 - u3*py0;
    v2f ni0 = u0*xi01 + u1*xe01 + u2*py0 + u3*px0;
    v2f ne2 = u0*xe23 - u1*xi23 + u2*px2 - u3*py2;
    v2f ni2 = u0*xi23 + u1*xe23 + u2*py2 + u3*px2;
    xe01 = ne0; xi01 = ni0; xe23 = ne2; xi23 = ni2;
}

__global__ __launch_bounds__(256, 1) void qlstm_kernel(Args a) {
    const int b    = blockIdx.x;
    const int tid  = threadIdx.x;
    const int lane = tid & 63;
    const int wv   = tid >> 6;          // wave id == gate id (f,i,g,o)

    __shared__ float Ax[TT][32];                       // x-part of angles (+bias), all t
    __shared__ __align__(16) float hH[16][HID];        // h history ring (flushed /16 steps)
    __shared__ __align__(16) float4 uab[4][2][8];      // SU(2) (ax,ay,bx,by) per gate
    __shared__ __align__(16) float expL[32];           // <Z_q>, layout [q][gate]

    const int a_ang = tid >> 3, p = tid & 7;
    const int g_ang = a_ang >> 3, q_ang = a_ang & 7;
    v2f whr2[8][2];
    {
        const float* Wg = a.W[g_ang] + q_ang * CD + IND;
#pragma unroll
        for (int k = 0; k < 8; ++k) {
            int base = p * 32 + ((4 * (k + p)) & 31);
            whr2[k][0] = pk(Wg[base + 0], Wg[base + 1]);
            whr2[k][1] = pk(Wg[base + 2], Wg[base + 3]);
        }
    }
    // output-stage: pack U rows across gate pairs (f,i) and (g,o)
    v2f ur2a[8], ur2b[8], cb2a, cb2b;
#pragma unroll
    for (int k = 0; k < 8; ++k) {
        ur2a[k] = pk(a.Uo[0][tid * 8 + k], a.Uo[1][tid * 8 + k]);
        ur2b[k] = pk(a.Uo[2][tid * 8 + k], a.Uo[3][tid * 8 + k]);
    }
    cb2a = pk(a.cb[0][tid], a.cb[1][tid]);
    cb2b = pk(a.cb[2][tid], a.cb[3][tid]);

    // ---- SU(2) parameter unitaries alpha,beta = Rz*Ry*Rx (once) ----
    if (tid < 64) {
        int g = tid >> 4, d = (tid >> 3) & 1, q = tid & 7;
        const float* qp = a.qp[g] + q * 6 + d * 3;
        float s0, c0, s1, c1, s2, c2;
        sincosf(0.5f * qp[0], &s0, &c0);
        sincosf(0.5f * qp[1], &s1, &c1);
        sincosf(0.5f * qp[2], &s2, &c2);
        C2 aX{c0, 0.f}, bX{0.f, -s0};
        C2 aY{c1, 0.f}, bY{-s1, 0.f};
        C2 aB = csub(cmul(aY, aX), cmul(bY, conjc(bX)));
        C2 bB = cadd(cmul(aY, bX), cmul(bY, conjc(aX)));
        C2 aZ{c2, -s2};
        C2 al = cmul(aZ, aB), be = cmul(aZ, bB);
        uab[g][d][q] = make_float4(al.x, al.y, be.x, be.y);
    }

    // ---- x-part of angles for all timesteps (once) ----
    for (int rep = 0; rep < 8; ++rep) {
        int idx = rep * 256 + tid;
        int t = idx >> 5, aa = idx & 31;
        int gg = aa >> 3, qq = aa & 7;
        const float4* w4 = (const float4*)(a.W[gg] + qq * CD);
        const float4* x4 = (const float4*)(a.x + (size_t)(t * BB + b) * IND);
        float acc = a.bb[gg][qq];
        for (int e = 0; e < IND / 4; ++e) {
            float4 xv = x4[e], wvv = w4[e];
            acc += xv.x * wvv.x + xv.y * wvv.y + xv.z * wvv.z + xv.w * wvv.w;
        }
        Ax[t][aa] = acc;
    }

    hH[15][tid] = 0.f;
    float creg = 0.f, h = 0.f;
    __syncthreads();

    // ---- d=0 unitaries prepacked for the v-build:
    // Vx = pA*c + pB*s = (v0x, v1x); Vy = pC*c + pD*s = (v0y, v1y)
    v2f pA[8], pB[8], pC[8], pD[8];
#pragma unroll
    for (int q = 0; q < 8; ++q) {
        float4 u = uab[wv][0][q];
        float ax = rfl(u.x), ay = rfl(u.y), bx = rfl(u.z), by = rfl(u.w);
        pA[q] = pk(ax, -bx);
        pB[q] = pk(by, -ay);
        pC[q] = pk(ay, by);
        pD[q] = pk(-bx, -ax);
    }
    // ---- d=1 lane-gate unitaries, sign-baked per lane (scalars, splat in pk ops) ----
    float gA[6][4];
#pragma unroll
    for (int qi = 0; qi < 6; ++qi) {
        float4 u = uab[wv][1][qi + 2];
        bool bit = (lane >> (5 - qi)) & 1;
        gA[qi][0] = u.x;
        gA[qi][1] = bit ? -u.y : u.y;
        gA[qi][2] = bit ? -u.z : u.z;
        gA[qi][3] = u.w;
    }
    // ---- d=1 reg-gate unitaries (uniform scalars + mixed-sign packs for qubit1) ----
    float q0ax, q0ay, q0bx, q0by;
    float q1ax, q1by;
    v2f q1aym, q1ayp, q1bxm;
    {
        float4 u0 = uab[wv][1][0], u1 = uab[wv][1][1];
        q0ax = rfl(u0.x); q0ay = rfl(u0.y); q0bx = rfl(u0.z); q0by = rfl(u0.w);
        q1ax = rfl(u1.x); q1by = rfl(u1.w);
        float ay = rfl(u1.y), bx = rfl(u1.z);
        q1aym = pk(-ay, ay);
        q1ayp = pk(ay, -ay);
        q1bxm = pk(bx, -bx);
    }

    // ---- d=0 CNOT chain folded into init (proven R11): selector bits ----
    const bool st3 = ((lane >> 4) ^ (lane >> 5)) & 1;
    const bool st4 = ((lane >> 3) ^ (lane >> 4)) & 1;
    const bool st5 = ((lane >> 2) ^ (lane >> 3)) & 1;
    const bool st6 = ((lane >> 1) ^ (lane >> 2)) & 1;
    const bool st7 = (lane ^ (lane >> 1)) & 1;
    const bool sp2 = (lane >> 5) & 1;
    const bool sp7 = lane & 1;

    // ---- measurement sign masks (proven R10) ----
    unsigned sg0, sg2, sg3, sg4, sg5, sg6, sg7;
    {
        auto par31 = [](int v) -> unsigned { return (unsigned)(__popc(v) & 1) << 31; };
        sg0 = par31(lane & 63);
        sg2 = par31(lane & 32);
        sg3 = par31(lane & 48);
        sg4 = par31(lane & 56);
        sg5 = par31(lane & 60);
        sg6 = par31(lane & 62);
        sg7 = sg0;
    }

    for (int t = 0; t < TT; ++t) {
        // ---- angle stage (packed dot) ----
        const int rowPrev = (t + 15) & 15;
        const float* hrow = hH[rowPrev];
        v2f acc2 = pk(0.f, 0.f);
#pragma unroll
        for (int k = 0; k < 8; ++k) {
            int base = p * 32 + ((4 * (k + p)) & 31);
            const float4 hv = *reinterpret_cast<const float4*>(&hrow[base]);
            acc2 = acc2 + pk(hv.x, hv.y) * whr2[k][0] + pk(hv.z, hv.w) * whr2[k][1];
        }
        float acc = acc2.x + acc2.y;
        acc += lx<1>(acc);
        acc += lx<2>(acc);
        acc += lx<4>(acc);
        float ang = 0.5f * (acc + Ax[t][a_ang]);
        float cA = __cosf(ang), sA = __sinf(ang);
        float cs_c[8], cs_s[8];
#pragma unroll
        for (int q = 0; q < 8; ++q) {
            cs_c[q] = bcast_lane(cA, q * 8);
            cs_s[q] = bcast_lane(sA, q * 8);
        }

        // ---- packed v-build: Vx[q]=(v0x,v1x), Vy[q]=(v0y,v1y) ----
        v2f Vx[8], Vy[8];
#pragma unroll
        for (int q = 0; q < 8; ++q) {
            Vx[q] = pA[q] * cs_c[q] + pB[q] * cs_s[q];
            Vy[q] = pC[q] * cs_c[q] + pD[q] * cs_s[q];
        }

        // ---- init product at M^-1(p) (d=0 CNOT folded; tree part-packed) ----
        v2f xe01, xi01, xe23, xi23;
        {
            C2 f3{ st3 ? Vx[3].y : Vx[3].x, st3 ? Vy[3].y : Vy[3].x };
            C2 f4{ st4 ? Vx[4].y : Vx[4].x, st4 ? Vy[4].y : Vy[4].x };
            C2 f5{ st5 ? Vx[5].y : Vx[5].x, st5 ? Vy[5].y : Vy[5].x };
            C2 f6{ st6 ? Vx[6].y : Vx[6].x, st6 ? Vy[6].y : Vy[6].x };
            C2 f7{ st7 ? Vx[7].y : Vx[7].x, st7 ? Vy[7].y : Vy[7].x };
            C2 c5 = cmul(cmul(cmul(f3, f4), cmul(f5, f6)), f7);
            // f2 pair (r even, r odd): (f2a, f2b) = sp2 ? (v1,v0) : (v0,v1)
            v2f f2re = sp2 ? swp(Vx[2]) : Vx[2];
            v2f f2im = sp2 ? swp(Vy[2]) : Vy[2];
            // c2pair = c5 * f2pair
            v2f c2re = c5.x * f2re - c5.y * f2im;
            v2f c2im = c5.x * f2im + c5.y * f2re;
            // f1 pair (f1a, f1b) = sp7 ? (v1,v0) : (v0,v1); f0a/f0b scalars
            v2f f1re = sp7 ? swp(Vx[1]) : Vx[1];
            v2f f1im = sp7 ? swp(Vy[1]) : Vy[1];
            float f0ax = sp7 ? Vx[0].y : Vx[0].x, f0ay = sp7 ? Vy[0].y : Vy[0].x;
            float f0bx = sp7 ? Vx[0].x : Vx[0].y, f0by = sp7 ? Vy[0].x : Vy[0].y;
            // (uu,m1) = f1pair * f0a ; (ww,m2) = swap(f1pair) * f0b
            v2f uure = f1re * f0ax - f1im * f0ay;
            v2f uuim = f1re * f0ay + f1im * f0ax;
            v2f s1re = swp(f1re), s1im = swp(f1im);
            v2f wwre = s1re * f0bx - s1im * f0by;
            v2f wwim = s1re * f0by + s1im * f0bx;
            // amps: (a0,a1) = c2pair*(uu,m1); (a2,a3) = c2pair*(ww,m2)
            xe01 = c2re * uure - c2im * uuim;
            xi01 = c2re * uuim + c2im * uure;
            xe23 = c2re * wwre - c2im * wwim;
            xi23 = c2re * wwim + c2im * wwre;
        }

        // ---- d=1 reg-gates (packed) ----
        { // qubit 0: pairs (0,2),(1,3) -> aligned across (01)/(23)
            v2f ne01 = q0ax*xe01 - q0ay*xi01 + q0bx*xe23 - q0by*xi23;
            v2f ni01 = q0ax*xi01 + q0ay*xe01 + q0bx*xi23 + q0by*xe23;
            v2f ne23 = -q0bx*xe01 - q0by*xi01 + q0ax*xe23 + q0ay*xi23;
            v2f ni23 = -q0bx*xi01 + q0by*xe01 + q0ax*xi23 - q0ay*xe23;
            xe01 = ne01; xi01 = ni01; xe23 = ne23; xi23 = ni23;
        }
        { // qubit 1: pairs (0,1),(2,3) -> within-pair via swap + mixed-sign packs
            v2f se01 = swp(xe01), si01 = swp(xi01);
            v2f se23 = swp(xe23), si23 = swp(xi23);
            v2f ne01 = q1ax*xe01 + q1aym*xi01 + q1bxm*se01 - q1by*si01;
            v2f ni01 = q1ax*xi01 + q1ayp*xe01 + q1bxm*si01 + q1by*se01;
            v2f ne23 = q1ax*xe23 + q1aym*xi23 + q1bxm*se23 - q1by*si23;
            v2f ni23 = q1ax*xi23 + q1ayp*xe23 + q1bxm*si23 + q1by*se23;
            xe01 = ne01; xi01 = ni01; xe23 = ne23; xi23 = ni23;
        }
        // ---- d=1 lane-gates (packed) ----
        gate_lane_pk<32>(xe01, xi01, xe23, xi23, gA[0][0], gA[0][1], gA[0][2], gA[0][3]);
        gate_lane_pk<16>(xe01, xi01, xe23, xi23, gA[1][0], gA[1][1], gA[1][2], gA[1][3]);
        gate_lane_pk< 8>(xe01, xi01, xe23, xi23, gA[2][0], gA[2][1], gA[2][2], gA[2][3]);
        gate_lane_pk< 4>(xe01, xi01, xe23, xi23, gA[3][0], gA[3][1], gA[3][2], gA[3][3]);
        gate_lane_pk< 2>(xe01, xi01, xe23, xi23, gA[4][0], gA[4][1], gA[4][2], gA[4][3]);
        gate_lane_pk< 1>(xe01, xi01, xe23, xi23, gA[5][0], gA[5][1], gA[5][2], gA[5][3]);

        // ---- expvals: sign masks + full butterfly (packed adds) ----
        v2f pr01 = xe01 * xe01 + xi01 * xi01;
        v2f pr23 = xe23 * xe23 + xi23 * xi23;
        float pr0 = pr01.x, pr1 = pr01.y, pr2 = pr23.x, pr3 = pr23.y;
        float Bc = pr0 - pr1 + pr2 - pr3;
        float Dc = pr0 - pr1 - pr2 + pr3;
        v2f zA = pk(sgnx(Bc, sg0), Dc);
        v2f zB = pk(sgnx(Dc, sg2), sgnx(Dc, sg3));
        v2f zC = pk(sgnx(Dc, sg4), sgnx(Dc, sg5));
        v2f zD = pk(sgnx(Dc, sg6), sgnx(Dc, sg7));
        zA = zA + lx2<1>(zA);  zB = zB + lx2<1>(zB);  zC = zC + lx2<1>(zC);  zD = zD + lx2<1>(zD);
        zA = zA + lx2<2>(zA);  zB = zB + lx2<2>(zB);  zC = zC + lx2<2>(zC);  zD = zD + lx2<2>(zD);
        zA = zA + lx2<4>(zA);  zB = zB + lx2<4>(zB);  zC = zC + lx2<4>(zC);  zD = zD + lx2<4>(zD);
        zA = zA + lx2<8>(zA);  zB = zB + lx2<8>(zB);  zC = zC + lx2<8>(zC);  zD = zD + lx2<8>(zD);
        zA = zA + lx2<16>(zA); zB = zB + lx2<16>(zB); zC = zC + lx2<16>(zC); zD = zD + lx2<16>(zD);
        zA = zA + lx2<32>(zA); zB = zB + lx2<32>(zB); zC = zC + lx2<32>(zC); zD = zD + lx2<32>(zD);
        if (lane == 0) {
            expL[0*4 + wv] = zA.x; expL[1*4 + wv] = zA.y;
            expL[2*4 + wv] = zB.x; expL[3*4 + wv] = zB.y;
            expL[4*4 + wv] = zC.x; expL[5*4 + wv] = zC.y;
            expL[6*4 + wv] = zD.x; expL[7*4 + wv] = zD.y;
        }
        __syncthreads();

        // ---- output projection (packed across gate pairs) + LSTM pointwise ----
        const float4* eL4 = (const float4*)expL;   // eL4[k] = (z_k gate0..3)
        v2f og2a = cb2a, og2b = cb2b;
#pragma unroll
        for (int k = 0; k < 8; ++k) {
            float4 e4 = eL4[k];
            og2a = og2a + pk(e4.x, e4.y) * ur2a[k];
            og2b = og2b + pk(e4.z, e4.w) * ur2b[k];
        }
        float fg = sigm(og2a.x);
        float ig = sigm(og2a.y);
        float gg = tanh_fast(og2b.x);
        float oo = sigm(og2b.y);
        creg = fg * creg + ig * gg;
        h = oo * tanh_fast(creg);

        hH[t & 15][tid] = h;
        if ((t & 15) == 15) {
            int t0 = t - 15;
#pragma unroll
            for (int r = 0; r < 16; ++r)
                a.out[(size_t)((t0 + r) * BB + b) * HID + tid] = hH[r][tid];
        }
        __syncthreads();
    }

    a.out[(size_t)TT * BB * HID + (size_t)b * HID + tid] = h;
    a.out[(size_t)TT * BB * HID + (size_t)BB * HID + (size_t)b * HID + tid] = creg;
}

extern "C" void kernel_launch(void* const* d_in, const int* in_sizes, int n_in,
                              void* d_out, int out_size, void* d_ws, size_t ws_size,
                              hipStream_t stream) {
    (void)in_sizes; (void)n_in; (void)out_size; (void)d_ws; (void)ws_size;
    Args ar;
    ar.x = (const float*)d_in[0];
    for (int g = 0; g < 4; ++g) {
        ar.W[g]  = (const float*)d_in[1 + 5 * g];
        ar.bb[g] = (const float*)d_in[2 + 5 * g];
        ar.qp[g] = (const float*)d_in[3 + 5 * g];
        ar.Uo[g] = (const float*)d_in[4 + 5 * g];
        ar.cb[g] = (const float*)d_in[5 + 5 * g];
    }
    ar.out = (float*)d_out;
    qlstm_kernel<<<dim3(BB), dim3(256), 0, stream>>>(ar);
}